// Round 8
// baseline (702.731 us; speedup 1.0000x reference)
//
#include <hip/hip_runtime.h>
#include <hip/hip_bf16.h>

#define D 128
#define N_TAXON 100000
#define N_SOTU 200000
#define E_HP 200000
#define E_RH 2000000
#define OUTC 64
#define NBUCK 25      // ceil(N_SOTU / 8192)
#define BSHIFT 13

typedef __hip_bfloat16 bf16;
typedef __bf16 bf16v8 __attribute__((ext_vector_type(8)));
typedef float f32x4 __attribute__((ext_vector_type(4)));
typedef int i32x4 __attribute__((ext_vector_type(4)));
typedef unsigned u32x2 __attribute__((ext_vector_type(2)));

union Frag { i32x4 i; bf16v8 v; };

__device__ __forceinline__ float bflo(unsigned u) { return __uint_as_float(u << 16); }
__device__ __forceinline__ float bfhi(unsigned u) { return __uint_as_float(u & 0xffff0000u); }

__device__ __forceinline__ unsigned short f2bf(float x) {
    unsigned u = __float_as_uint(x);
    unsigned r = (u + 0x7fffu + ((u >> 16) & 1u)) >> 16;   // round-to-nearest-even
    return (unsigned short)r;
}
__device__ __forceinline__ unsigned packbf(float a, float b) {
    return (unsigned)f2bf(a) | ((unsigned)f2bf(b) << 16);
}

// weight a-frag read from pre-swizzled global image; col<128, frag = Wt[col][32ks+8g..+7]
__device__ __forceinline__ i32x4 ldWfrag(const unsigned short* __restrict__ Wt,
                                         int col, int ks, int g) {
    int off = ((col << 8) + (ks << 6) + (g << 4)) ^ ((col & 7) << 4);
    return *(const i32x4*)((const char*)Wt + off);
}

// ---------------- fused: hp degree + rh bucket histogram + bucket prefix ----------------
__global__ __launch_bounds__(256) void countAll_kernel(const int* __restrict__ hp_dst,
                                                       const int* __restrict__ rh_dst,
                                                       unsigned* __restrict__ cnt_t,
                                                       unsigned* __restrict__ bcnt,
                                                       unsigned* __restrict__ bcursor,
                                                       unsigned* __restrict__ ticket)
{
    __shared__ unsigned hist[NBUCK];
    for (int i = threadIdx.x; i < NBUCK; i += 256) hist[i] = 0;
    __syncthreads();
    int stride = gridDim.x * 256;
    for (int e = blockIdx.x * 256 + threadIdx.x; e < E_HP; e += stride)
        atomicAdd(&cnt_t[hp_dst[e]], 1u);
    for (int e = blockIdx.x * 256 + threadIdx.x; e < E_RH; e += stride)
        atomicAdd(&hist[rh_dst[e] >> BSHIFT], 1u);
    __syncthreads();
    if (threadIdx.x < NBUCK) atomicAdd(&bcnt[threadIdx.x], hist[threadIdx.x]);
    __syncthreads();
    if (threadIdx.x == 0) {
        __threadfence();
        unsigned t = atomicAdd(ticket, 1u);
        if (t == gridDim.x - 1) {        // last block: 25-entry exclusive prefix
            unsigned acc = 0;
            for (int b = 0; b < NBUCK; ++b) {
                unsigned v = atomicAdd(&bcnt[b], 0u);
                bcursor[b] = acc; acc += v;
            }
        }
    }
}

// ---------------- rh: partition edges into dst-buckets + per-dst count ----------------
__global__ __launch_bounds__(256) void partition_kernel(
    const int* __restrict__ src, const int* __restrict__ dst,
    unsigned* __restrict__ bcursor, unsigned* __restrict__ cnt_s,
    unsigned long long* __restrict__ ebuf, int n)
{
    __shared__ unsigned hist[NBUCK];
    __shared__ unsigned lcur[NBUCK];
    int base = blockIdx.x * 2048;
    for (int i = threadIdx.x; i < NBUCK; i += 256) hist[i] = 0;
    __syncthreads();
    int s[8], d[8];
#pragma unroll
    for (int k = 0; k < 8; ++k) {
        int e = base + k * 256 + threadIdx.x;
        if (e < n) {
            s[k] = src[e]; d[k] = dst[e];
            atomicAdd(&hist[d[k] >> BSHIFT], 1u);
            atomicAdd(&cnt_s[d[k]], 1u);
        } else d[k] = -1;
    }
    __syncthreads();
    if (threadIdx.x < NBUCK)
        lcur[threadIdx.x] = atomicAdd(&bcursor[threadIdx.x], hist[threadIdx.x]);
    __syncthreads();
#pragma unroll
    for (int k = 0; k < 8; ++k) {
        if (d[k] >= 0) {
            unsigned slot = atomicAdd(&lcur[d[k] >> BSHIFT], 1u);
            ebuf[slot] = ((unsigned long long)(unsigned)d[k] << 32) | (unsigned)s[k];
        }
    }
}

// ---------------- combined 3-phase exclusive scan over [cnt_t ; cnt_s] ----------------
__global__ __launch_bounds__(256) void scanA_kernel(const unsigned* __restrict__ cnt,
                                                    unsigned* __restrict__ bsum, int n)
{
    int lane = threadIdx.x & 63, wv = threadIdx.x >> 6;
    __shared__ unsigned ws[4];
    int i = blockIdx.x * 256 + threadIdx.x;
    unsigned v = (i < n) ? cnt[i] : 0u;
    for (int off = 1; off < 64; off <<= 1) v += __shfl_xor(v, off, 64);
    if (lane == 0) ws[wv] = v;
    __syncthreads();
    if (threadIdx.x == 0) bsum[blockIdx.x] = ws[0] + ws[1] + ws[2] + ws[3];
}

// handles nb <= 2048 (2 elements per thread)
__global__ __launch_bounds__(1024) void scanB_kernel(unsigned* __restrict__ bsum, int nb,
                                                     unsigned* __restrict__ total_out)
{
    int lane = threadIdx.x & 63, wv = threadIdx.x >> 6;
    __shared__ unsigned wsum[16];
    int t = threadIdx.x;
    unsigned v0 = (2 * t     < nb) ? bsum[2 * t]     : 0u;
    unsigned v1 = (2 * t + 1 < nb) ? bsum[2 * t + 1] : 0u;
    unsigned v = v0 + v1;
    unsigned s = v;
    for (int off = 1; off < 64; off <<= 1) {
        unsigned tt = __shfl_up(s, off, 64);
        if (lane >= off) s += tt;
    }
    if (lane == 63) wsum[wv] = s;
    __syncthreads();
    unsigned woff = 0, tot = 0;
    for (int w = 0; w < 16; ++w) { if (w < wv) woff += wsum[w]; tot += wsum[w]; }
    unsigned ex = woff + s - v;
    if (2 * t     < nb) bsum[2 * t]     = ex;
    if (2 * t + 1 < nb) bsum[2 * t + 1] = ex + v0;
    if (t == 0) *total_out = tot;
}

__global__ __launch_bounds__(256) void scanC_kernel(const unsigned* __restrict__ cnt,
                                                    const unsigned* __restrict__ bsum,
                                                    unsigned* __restrict__ row_ptr,
                                                    unsigned* __restrict__ cursor, int n)
{
    int lane = threadIdx.x & 63, wv = threadIdx.x >> 6;
    __shared__ unsigned wsum[4];
    int i = blockIdx.x * 256 + threadIdx.x;
    unsigned v = (i < n) ? cnt[i] : 0u;
    unsigned s = v;
    for (int off = 1; off < 64; off <<= 1) {
        unsigned t = __shfl_up(s, off, 64);
        if (lane >= off) s += t;
    }
    if (lane == 63) wsum[wv] = s;
    __syncthreads();
    unsigned woff = bsum[blockIdx.x];
    for (int w = 0; w < wv; ++w) woff += wsum[w];
    if (i < n) { unsigned p = woff + s - v; row_ptr[i] = p; cursor[i] = p; }
}

// ---------------- fused CSR fills (hp raw edges + rh from ebuf) ----------------
__global__ __launch_bounds__(256) void fills_kernel(const int* __restrict__ hp_src,
                                                    const int* __restrict__ hp_dst,
                                                    const unsigned long long* __restrict__ ebuf,
                                                    unsigned* __restrict__ cursor,
                                                    int* __restrict__ sorted_all)
{
    int stride = gridDim.x * 256;
    for (int i = blockIdx.x * 256 + threadIdx.x; i < E_HP + E_RH; i += stride) {
        if (i < E_HP) {
            unsigned pos = atomicAdd(&cursor[hp_dst[i]], 1u);
            sorted_all[pos] = hp_src[i];
        } else {
            unsigned long long v = ebuf[i - E_HP];
            unsigned pos = atomicAdd(&cursor[N_TAXON + (unsigned)(v >> 32)], 1u);
            sorted_all[pos] = (int)(unsigned)v;
        }
    }
}

// ---------------- all weights: transpose + bf16 + XOR-swizzle in one kernel ----------------
__global__ __launch_bounds__(256) void wprep_all_kernel(
    const float* __restrict__ W1l, const float* __restrict__ W1r,
    const float* __restrict__ W2l, const float* __restrict__ W2r,
    const float* __restrict__ W3l, const float* __restrict__ W3r,
    const float* __restrict__ Wlin, unsigned short* __restrict__ wtbase)
{
    int e = blockIdx.x * 256 + threadIdx.x;
    if (e >= 6 * 16384 + 8192) return;
    const float* srcs[7] = { W1l, W1r, W2l, W2r, W3l, W3r, Wlin };
    int m = e >> 14;
    int local = (m < 6) ? (e & 16383) : (e - 98304);
    int N = (m < 6) ? 128 : 64;
    int k = local / N, col = local - k * N;
    unsigned short* dst = wtbase + ((m < 6) ? m * 16384 : 98304);
    dst[(col * 128 + k) ^ ((col & 7) << 3)] = f2bf(srcs[m][local]);
}

// ---------------- cast f32 rows -> packed bf16 pairs ----------------
__global__ __launch_bounds__(256) void cast_kernel(const float* __restrict__ x,
                                                   unsigned* __restrict__ xb, int npairs)
{
    int stride = gridDim.x * 256;
    for (int i = blockIdx.x * 256 + threadIdx.x; i < npairs; i += stride) {
        float2 v = ((const float2*)x)[i];
        xb[i] = packbf(v.x, v.y);
    }
}

// ---------------- mean gather: out[r] = mean_nbr(src_rows), wave-independent ----------------
__global__ __launch_bounds__(256) void aggMean_kernel(
    const unsigned* __restrict__ src_rows,   // [*][64] bf16 pairs
    const unsigned* __restrict__ rp,         // row_ptr (possibly offset)
    const int* __restrict__ nbr,
    unsigned* __restrict__ outm)             // [nrows][64]
{
    int wave = threadIdx.x >> 6, lane = threadIdx.x & 63;
    int r = blockIdx.x * 4 + wave;
    unsigned beg = rp[r], end = rp[r + 1];
    float a0 = 0.f, a1 = 0.f;
    unsigned u = beg;
    for (; u + 4 <= end; u += 4) {
        int j0 = nbr[u], j1 = nbr[u + 1], j2 = nbr[u + 2], j3 = nbr[u + 3];
        unsigned p0 = src_rows[(size_t)j0 * 64 + lane];
        unsigned p1 = src_rows[(size_t)j1 * 64 + lane];
        unsigned p2 = src_rows[(size_t)j2 * 64 + lane];
        unsigned p3 = src_rows[(size_t)j3 * 64 + lane];
        a0 += bflo(p0) + bflo(p1) + bflo(p2) + bflo(p3);
        a1 += bfhi(p0) + bfhi(p1) + bfhi(p2) + bfhi(p3);
    }
    for (; u < end; ++u) {
        unsigned p = src_rows[(size_t)nbr[u] * 64 + lane];
        a0 += bflo(p); a1 += bfhi(p);
    }
    unsigned c = end - beg;
    float inv = 1.f / (float)(c ? c : 1u);
    outm[(size_t)r * 64 + lane] = packbf(a0 * inv, a1 * inv);
}

// ---------------- dual GEMM: out = relu(A1@WtA + A2@WtB + bias), bf16 out ----------------
template<bool A2F32>
__global__ __launch_bounds__(256) void gemmDual_kernel(
    const unsigned* __restrict__ A1,         // [M][64] bf16 pairs
    const void* __restrict__ A2,             // [M][64] u32 or [M][128] f32
    const unsigned short* __restrict__ WtA, const unsigned short* __restrict__ WtB,
    const float* __restrict__ bias, unsigned* __restrict__ Yout, int M)
{
    __shared__ char sW[65536];
    for (int c = threadIdx.x; c < 4096; c += 256)
        ((i32x4*)sW)[c] = (c < 2048) ? ((const i32x4*)WtA)[c] : ((const i32x4*)WtB)[c - 2048];
    __syncthreads();

    int wave = threadIdx.x >> 6, lane = threadIdx.x & 63;
    int ln = lane & 15, g = lane >> 4;
    int row = blockIdx.x * 64 + wave * 16 + ln;
    int rl = row < M ? row : M - 1;
    int swz = (ln & 7) << 4;

    f32x4 acc[8];
#pragma unroll
    for (int cf = 0; cf < 8; ++cf) acc[cf] = ((const f32x4*)bias)[cf * 4 + g];

    const i32x4* a1r = (const i32x4*)(A1 + (size_t)rl * 64);
#pragma unroll
    for (int ks = 0; ks < 4; ++ks) {
        Frag mf; mf.i = a1r[ks * 4 + g];
        Frag xf;
        if (A2F32) {
            const f32x4* xr = (const f32x4*)((const float*)A2 + (size_t)rl * 128);
            f32x4 fa = xr[ks * 8 + g * 2], fb = xr[ks * 8 + g * 2 + 1];
            i32x4 t = { (int)packbf(fa.x, fa.y), (int)packbf(fa.z, fa.w),
                        (int)packbf(fb.x, fb.y), (int)packbf(fb.z, fb.w) };
            xf.i = t;
        } else {
            xf.i = ((const i32x4*)((const unsigned*)A2 + (size_t)rl * 64))[ks * 4 + g];
        }
#pragma unroll
        for (int cf = 0; cf < 8; ++cf) {
            int off = (((cf * 16 + ln) << 8) + (ks << 6) + (g << 4)) ^ swz;
            Frag wa; wa.i = *(const i32x4*)(sW + off);
            Frag wb; wb.i = *(const i32x4*)(sW + 32768 + off);
            acc[cf] = __builtin_amdgcn_mfma_f32_16x16x32_bf16(wa.v, mf.v, acc[cf], 0, 0, 0);
            acc[cf] = __builtin_amdgcn_mfma_f32_16x16x32_bf16(wb.v, xf.v, acc[cf], 0, 0, 0);
        }
    }

    if (row < M) {
        unsigned* orow = Yout + (size_t)row * 64;
#pragma unroll
        for (int cf = 0; cf < 8; ++cf) {
            u32x2 o;
            o.x = packbf(fmaxf(acc[cf][0], 0.f), fmaxf(acc[cf][1], 0.f));
            o.y = packbf(fmaxf(acc[cf][2], 0.f), fmaxf(acc[cf][3], 0.f));
            *(u32x2*)(orow + cf * 8 + g * 2) = o;
        }
    }
}

// ---------------- tail: h2 = relu(meanH@W3l + sotu_h@W3r + b3) (LDS); out = h2@Wlin + blin ----------------
// M divisible by 64; uniform work, weights via global ldWfrag
__global__ __launch_bounds__(256) void tail_kernel(
    const unsigned* __restrict__ meanH, const unsigned* __restrict__ sotu_h,
    const unsigned short* __restrict__ Wt3l, const unsigned short* __restrict__ Wt3r,
    const unsigned short* __restrict__ Wtlin,
    const float* __restrict__ b3, const float* __restrict__ blin,
    float* __restrict__ out, int M)
{
    __shared__ unsigned h2[64 * 64];   // 16KB, XOR-swizzled
    int wave = threadIdx.x >> 6, lane = threadIdx.x & 63;
    int ln = lane & 15, g = lane >> 4;
    int lrow = wave * 16 + ln;
    int row = blockIdx.x * 64 + lrow;

    f32x4 acc[8];
#pragma unroll
    for (int cf = 0; cf < 8; ++cf) acc[cf] = ((const f32x4*)b3)[cf * 4 + g];

    const i32x4* mr = (const i32x4*)(meanH + (size_t)row * 64);
    const i32x4* sr = (const i32x4*)(sotu_h + (size_t)row * 64);
#pragma unroll
    for (int ks = 0; ks < 4; ++ks) {
        Frag mf; mf.i = mr[ks * 4 + g];
        Frag sf; sf.i = sr[ks * 4 + g];
#pragma unroll
        for (int cf = 0; cf < 8; ++cf) {
            int col = cf * 16 + ln;
            Frag wl; wl.i = ldWfrag(Wt3l, col, ks, g);
            Frag wr; wr.i = ldWfrag(Wt3r, col, ks, g);
            acc[cf] = __builtin_amdgcn_mfma_f32_16x16x32_bf16(wl.v, mf.v, acc[cf], 0, 0, 0);
            acc[cf] = __builtin_amdgcn_mfma_f32_16x16x32_bf16(wr.v, sf.v, acc[cf], 0, 0, 0);
        }
    }
    int swz = (lrow & 7) << 2;
#pragma unroll
    for (int cf = 0; cf < 8; ++cf) {
        u32x2 o;
        o.x = packbf(fmaxf(acc[cf][0], 0.f), fmaxf(acc[cf][1], 0.f));
        o.y = packbf(fmaxf(acc[cf][2], 0.f), fmaxf(acc[cf][3], 0.f));
        *(u32x2*)&h2[lrow * 64 + ((cf * 8 + g * 2) ^ swz)] = o;
    }
    __syncthreads();

    f32x4 aL[4];
#pragma unroll
    for (int cf = 0; cf < 4; ++cf) aL[cf] = ((const f32x4*)blin)[cf * 4 + g];
#pragma unroll
    for (int ks = 0; ks < 4; ++ks) {
        Frag hf; hf.i = *(const i32x4*)&h2[lrow * 64 + ((ks * 16 + g * 4) ^ swz)];
#pragma unroll
        for (int cf = 0; cf < 4; ++cf) {
            Frag wf; wf.i = ldWfrag(Wtlin, cf * 16 + ln, ks, g);
            aL[cf] = __builtin_amdgcn_mfma_f32_16x16x32_bf16(wf.v, hf.v, aL[cf], 0, 0, 0);
        }
    }
    float* orow = out + (size_t)row * OUTC;
#pragma unroll
    for (int cf = 0; cf < 4; ++cf)
        *(f32x4*)(orow + cf * 16 + g * 4) = aL[cf];
}

extern "C" void kernel_launch(void* const* d_in, const int* in_sizes, int n_in,
                              void* d_out, int out_size, void* d_ws, size_t ws_size,
                              hipStream_t stream)
{
    const float* x_taxon = (const float*)d_in[0];
    const float* x_sotu  = (const float*)d_in[1];
    const int* hp_src = (const int*)d_in[2];
    const int* hp_dst = (const int*)d_in[3];
    const int* rh_src = (const int*)d_in[4];
    const int* rh_dst = (const int*)d_in[5];
    const float* W1l = (const float*)d_in[6];
    const float* W1r = (const float*)d_in[7];
    const float* b1  = (const float*)d_in[8];
    const float* W2l = (const float*)d_in[9];
    const float* W2r = (const float*)d_in[10];
    const float* b2  = (const float*)d_in[11];
    const float* W3l = (const float*)d_in[12];
    const float* W3r = (const float*)d_in[13];
    const float* b3  = (const float*)d_in[14];
    const float* Wlin = (const float*)d_in[15];
    const float* blin = (const float*)d_in[16];
    float* out = (float*)d_out;

    // ---- workspace layout (bytes), peak ~208 MB ----
    char* ws = (char*)d_ws;
    unsigned* xt_bf   = (unsigned*)(ws);                  // [100K][64] 25.6MB (dead after gemm_th)
    unsigned* taxon_h = (unsigned*)(ws + 25600000);       // 25.6MB (dead after aggH)
    unsigned* sotu_h  = (unsigned*)(ws);                  // 51.2MB overlays xt_bf+taxon_h
    unsigned* meanX   = (unsigned*)(ws + 51200000);       // [300K][64] 76.8MB
    unsigned* meanH   = (unsigned*)(ws + 128000000);      // [200K][64] 51.2MB
    unsigned long long* ebuf = (unsigned long long*)(ws + 179200000);  // 16MB
    int*      sorted_all = (int*)(ws + 195200000);        // 8.8MB
    unsigned* row_ptr = (unsigned*)(ws + 204000000);      // [300001]
    unsigned* cursor  = (unsigned*)(ws + 205200128);      // [300000]
    unsigned* cnt     = (unsigned*)(ws + 206400128);      // [300000]
    unsigned* bcnt    = (unsigned*)(ws + 207600128);      // [32]
    unsigned* bcursor = (unsigned*)(ws + 207600256);      // [32]; [31] = ticket
    unsigned* bsum    = (unsigned*)(ws + 207600384);      // [2048]
    unsigned short* wtbase = (unsigned short*)(ws + 207608576);
    unsigned* cnt_t = cnt;
    unsigned* cnt_s = cnt + N_TAXON;
    unsigned* ticket = bcursor + 31;
    unsigned short* Wt1l = wtbase;
    unsigned short* Wt1r = wtbase + 16384;
    unsigned short* Wt2l = wtbase + 32768;
    unsigned short* Wt2r = wtbase + 49152;
    unsigned short* Wt3l = wtbase + 65536;
    unsigned short* Wt3r = wtbase + 81920;
    unsigned short* Wtlin = wtbase + 98304;

    // zero cnt + bcnt + bcursor (incl. ticket)
    hipMemsetAsync(cnt, 0, 300000 * 4 + 256, stream);

    // ---- CSR build (unified 300K rows: hp rows 0..100K, rh rows 100K..300K) ----
    countAll_kernel<<<1024, 256, 0, stream>>>(hp_dst, rh_dst, cnt_t, bcnt, bcursor, ticket);
    partition_kernel<<<(E_RH + 2047) / 2048, 256, 0, stream>>>(rh_src, rh_dst, bcursor, cnt_s, ebuf, E_RH);
    {
        int n = N_TAXON + N_SOTU;
        int nb = (n + 255) / 256;   // 1172
        scanA_kernel<<<nb, 256, 0, stream>>>(cnt, bsum, n);
        scanB_kernel<<<1, 1024, 0, stream>>>(bsum, nb, row_ptr + n);
        scanC_kernel<<<nb, 256, 0, stream>>>(cnt, bsum, row_ptr, cursor, n);
    }
    fills_kernel<<<2048, 256, 0, stream>>>(hp_src, hp_dst, ebuf, cursor, sorted_all);

    // ---- weight prep + x_taxon cast ----
    wprep_all_kernel<<<(6 * 16384 + 8192 + 255) / 256, 256, 0, stream>>>(
        W1l, W1r, W2l, W2r, W3l, W3r, Wlin, wtbase);
    cast_kernel<<<25000, 256, 0, stream>>>(x_taxon, xt_bf, N_TAXON * 64);

    // ---- meanX over unified CSR (hp + rh in one dispatch, 300K rows) ----
    aggMean_kernel<<<(N_TAXON + N_SOTU) / 4, 256, 0, stream>>>(
        xt_bf, row_ptr, sorted_all, meanX);

    // ---- taxon_h = relu(meanX_hp@W1l + xt@W1r + b1) ----
    gemmDual_kernel<false><<<(N_TAXON + 63) / 64, 256, 0, stream>>>(
        meanX, xt_bf, Wt1l, Wt1r, b1, taxon_h, N_TAXON);

    // ---- meanH = mean_rh(taxon_h) ----
    aggMean_kernel<<<N_SOTU / 4, 256, 0, stream>>>(
        taxon_h, row_ptr + N_TAXON, sorted_all, meanH);

    // ---- sotu_h = relu(meanX_rh@W2l + x_sotu@W2r + b2) ----
    gemmDual_kernel<true><<<N_SOTU / 64, 256, 0, stream>>>(
        meanX + (size_t)N_TAXON * 64, x_sotu, Wt2l, Wt2r, b2, sotu_h, N_SOTU);

    // ---- tail: h2 (LDS) -> out ----
    tail_kernel<<<N_SOTU / 64, 256, 0, stream>>>(
        meanH, sotu_h, Wt3l, Wt3r, Wtlin, b3, blin, out, N_SOTU);
}

// Round 9
// 609.572 us; speedup vs baseline: 1.1528x; 1.1528x over previous
//
#include <hip/hip_runtime.h>
#include <hip/hip_bf16.h>

#define D 128
#define N_TAXON 100000
#define N_SOTU 200000
#define E_HP 200000
#define E_RH 2000000
#define OUTC 64
#define NBUCK 98      // ceil(N_SOTU / 2048)
#define BSHIFT 11

typedef __hip_bfloat16 bf16;
typedef __bf16 bf16v8 __attribute__((ext_vector_type(8)));
typedef float f32x4 __attribute__((ext_vector_type(4)));
typedef int i32x4 __attribute__((ext_vector_type(4)));
typedef unsigned u32x2 __attribute__((ext_vector_type(2)));

union Frag { i32x4 i; bf16v8 v; };

__device__ __forceinline__ float bflo(unsigned u) { return __uint_as_float(u << 16); }
__device__ __forceinline__ float bfhi(unsigned u) { return __uint_as_float(u & 0xffff0000u); }

__device__ __forceinline__ unsigned short f2bf(float x) {
    unsigned u = __float_as_uint(x);
    unsigned r = (u + 0x7fffu + ((u >> 16) & 1u)) >> 16;   // round-to-nearest-even
    return (unsigned short)r;
}
__device__ __forceinline__ unsigned packbf(float a, float b) {
    return (unsigned)f2bf(a) | ((unsigned)f2bf(b) << 16);
}

// weight a-frag read from pre-swizzled global image; col<128, frag = Wt[col][32ks+8g..+7]
__device__ __forceinline__ i32x4 ldWfrag(const unsigned short* __restrict__ Wt,
                                         int col, int ks, int g) {
    int off = ((col << 8) + (ks << 6) + (g << 4)) ^ ((col & 7) << 4);
    return *(const i32x4*)((const char*)Wt + off);
}

// ---------------- fused: hp degree + rh bucket histogram ----------------
__global__ __launch_bounds__(256) void countAll_kernel(const int* __restrict__ hp_dst,
                                                       const int* __restrict__ rh_dst,
                                                       unsigned* __restrict__ cnt_t,
                                                       unsigned* __restrict__ bcnt)
{
    __shared__ unsigned hist[NBUCK];
    if (threadIdx.x < NBUCK) hist[threadIdx.x] = 0;
    __syncthreads();
    int stride = gridDim.x * 256;
    for (int e = blockIdx.x * 256 + threadIdx.x; e < E_HP; e += stride)
        atomicAdd(&cnt_t[hp_dst[e]], 1u);
    for (int e = blockIdx.x * 256 + threadIdx.x; e < E_RH; e += stride)
        atomicAdd(&hist[rh_dst[e] >> BSHIFT], 1u);
    __syncthreads();
    if (threadIdx.x < NBUCK) atomicAdd(&bcnt[threadIdx.x], hist[threadIdx.x]);
}

// ---------------- tiny bucket prefix: bcursor (mutable) + bstart (preserved) ----------------
__global__ __launch_bounds__(128) void scan98_kernel(const unsigned* __restrict__ bcnt,
                                                     unsigned* __restrict__ bcursor,
                                                     unsigned* __restrict__ bstart)
{
    __shared__ unsigned v[NBUCK];
    if (threadIdx.x < NBUCK) v[threadIdx.x] = bcnt[threadIdx.x];
    __syncthreads();
    if (threadIdx.x == 0) {
        unsigned acc = 0;
        for (int b = 0; b < NBUCK; ++b) {
            unsigned t = v[b];
            bcursor[b] = acc; bstart[b] = acc; acc += t;
        }
        bstart[NBUCK] = acc;
    }
}

// ---------------- rh: partition edges into dst-buckets + per-dst count ----------------
__global__ __launch_bounds__(256) void partition_kernel(
    const int* __restrict__ src, const int* __restrict__ dst,
    unsigned* __restrict__ bcursor, unsigned* __restrict__ cnt_s,
    unsigned long long* __restrict__ ebuf, int n)
{
    __shared__ unsigned hist[NBUCK];
    __shared__ unsigned lcur[NBUCK];
    int base = blockIdx.x * 4096;
    if (threadIdx.x < NBUCK) hist[threadIdx.x] = 0;
    __syncthreads();
    int s[16], d[16];
#pragma unroll
    for (int k = 0; k < 16; ++k) {
        int e = base + k * 256 + threadIdx.x;
        if (e < n) {
            s[k] = src[e]; d[k] = dst[e];
            atomicAdd(&hist[d[k] >> BSHIFT], 1u);
            atomicAdd(&cnt_s[d[k]], 1u);
        } else d[k] = -1;
    }
    __syncthreads();
    if (threadIdx.x < NBUCK)
        lcur[threadIdx.x] = atomicAdd(&bcursor[threadIdx.x], hist[threadIdx.x]);
    __syncthreads();
#pragma unroll
    for (int k = 0; k < 16; ++k) {
        if (d[k] >= 0) {
            unsigned slot = atomicAdd(&lcur[d[k] >> BSHIFT], 1u);
            ebuf[slot] = ((unsigned long long)(unsigned)d[k] << 32) | (unsigned)s[k];
        }
    }
}

// ---------------- combined 3-phase exclusive scan over [cnt_t ; cnt_s] ----------------
__global__ __launch_bounds__(256) void scanA_kernel(const unsigned* __restrict__ cnt,
                                                    unsigned* __restrict__ bsum, int n)
{
    int lane = threadIdx.x & 63, wv = threadIdx.x >> 6;
    __shared__ unsigned ws[4];
    int i = blockIdx.x * 256 + threadIdx.x;
    unsigned v = (i < n) ? cnt[i] : 0u;
    for (int off = 1; off < 64; off <<= 1) v += __shfl_xor(v, off, 64);
    if (lane == 0) ws[wv] = v;
    __syncthreads();
    if (threadIdx.x == 0) bsum[blockIdx.x] = ws[0] + ws[1] + ws[2] + ws[3];
}

// handles nb <= 2048 (2 elements per thread)
__global__ __launch_bounds__(1024) void scanB_kernel(unsigned* __restrict__ bsum, int nb,
                                                     unsigned* __restrict__ total_out)
{
    int lane = threadIdx.x & 63, wv = threadIdx.x >> 6;
    __shared__ unsigned wsum[16];
    int t = threadIdx.x;
    unsigned v0 = (2 * t     < nb) ? bsum[2 * t]     : 0u;
    unsigned v1 = (2 * t + 1 < nb) ? bsum[2 * t + 1] : 0u;
    unsigned v = v0 + v1;
    unsigned s = v;
    for (int off = 1; off < 64; off <<= 1) {
        unsigned tt = __shfl_up(s, off, 64);
        if (lane >= off) s += tt;
    }
    if (lane == 63) wsum[wv] = s;
    __syncthreads();
    unsigned woff = 0, tot = 0;
    for (int w = 0; w < 16; ++w) { if (w < wv) woff += wsum[w]; tot += wsum[w]; }
    unsigned ex = woff + s - v;
    if (2 * t     < nb) bsum[2 * t]     = ex;
    if (2 * t + 1 < nb) bsum[2 * t + 1] = ex + v0;
    if (t == 0) *total_out = tot;
}

__global__ __launch_bounds__(256) void scanC_kernel(const unsigned* __restrict__ cnt,
                                                    const unsigned* __restrict__ bsum,
                                                    unsigned* __restrict__ row_ptr,
                                                    unsigned* __restrict__ cursor, int n)
{
    int lane = threadIdx.x & 63, wv = threadIdx.x >> 6;
    __shared__ unsigned wsum[4];
    int i = blockIdx.x * 256 + threadIdx.x;
    unsigned v = (i < n) ? cnt[i] : 0u;
    unsigned s = v;
    for (int off = 1; off < 64; off <<= 1) {
        unsigned t = __shfl_up(s, off, 64);
        if (lane >= off) s += t;
    }
    if (lane == 63) wsum[wv] = s;
    __syncthreads();
    unsigned woff = bsum[blockIdx.x];
    for (int w = 0; w < wv; ++w) woff += wsum[w];
    if (i < n) { unsigned p = woff + s - v; row_ptr[i] = p; cursor[i] = p; }
}

// ---------------- hp CSR fill (small, scattered is fine) ----------------
__global__ __launch_bounds__(256) void fill_hp_kernel(const int* __restrict__ src,
                                                      const int* __restrict__ dst,
                                                      unsigned* __restrict__ cursor,
                                                      int* __restrict__ sorted_all)
{
    int stride = gridDim.x * 256;
    for (int i = blockIdx.x * 256 + threadIdx.x; i < E_HP; i += stride) {
        unsigned pos = atomicAdd(&cursor[dst[i]], 1u);
        sorted_all[pos] = src[i];
    }
}

// ---------------- rh CSR fill: one block per bucket, LDS cursors, dense writes ----------------
__global__ __launch_bounds__(256) void fillB_kernel(const unsigned long long* __restrict__ ebuf,
                                                    const unsigned* __restrict__ row_ptr,
                                                    const unsigned* __restrict__ bstart,
                                                    int* __restrict__ sorted_all)
{
    __shared__ unsigned lcur[1 << BSHIFT];   // 8KB per-dst cursors for this bucket
    int c = blockIdx.x;
    int dbase = c << BSHIFT;
    for (int i = threadIdx.x; i < (1 << BSHIFT); i += 256) {
        int dd = dbase + i;
        lcur[i] = (dd < N_SOTU) ? row_ptr[N_TAXON + dd] : 0u;
    }
    __syncthreads();
    unsigned e0 = bstart[c], e1 = bstart[c + 1];
    for (unsigned e = e0 + threadIdx.x; e < e1; e += 256) {
        unsigned long long v = ebuf[e];
        unsigned dloc = (unsigned)(v >> 32) - dbase;
        unsigned pos = atomicAdd(&lcur[dloc], 1u);
        sorted_all[pos] = (int)(unsigned)v;
    }
}

// ---------------- all weights: transpose + bf16 + XOR-swizzle in one kernel ----------------
__global__ __launch_bounds__(256) void wprep_all_kernel(
    const float* __restrict__ W1l, const float* __restrict__ W1r,
    const float* __restrict__ W2l, const float* __restrict__ W2r,
    const float* __restrict__ W3l, const float* __restrict__ W3r,
    const float* __restrict__ Wlin, unsigned short* __restrict__ wtbase)
{
    int e = blockIdx.x * 256 + threadIdx.x;
    if (e >= 6 * 16384 + 8192) return;
    const float* srcs[7] = { W1l, W1r, W2l, W2r, W3l, W3r, Wlin };
    int m = e >> 14;
    int local = (m < 6) ? (e & 16383) : (e - 98304);
    int N = (m < 6) ? 128 : 64;
    int k = local / N, col = local - k * N;
    unsigned short* dst = wtbase + ((m < 6) ? m * 16384 : 98304);
    dst[(col * 128 + k) ^ ((col & 7) << 3)] = f2bf(srcs[m][local]);
}

// ---------------- cast f32 rows -> packed bf16 pairs ----------------
__global__ __launch_bounds__(256) void cast_kernel(const float* __restrict__ x,
                                                   unsigned* __restrict__ xb, int npairs)
{
    int stride = gridDim.x * 256;
    for (int i = blockIdx.x * 256 + threadIdx.x; i < npairs; i += stride) {
        float2 v = ((const float2*)x)[i];
        xb[i] = packbf(v.x, v.y);
    }
}

// ---------------- mean gather: out[r] = mean_nbr(src_rows), wave-independent ----------------
__global__ __launch_bounds__(256) void aggMean_kernel(
    const unsigned* __restrict__ src_rows,   // [*][64] bf16 pairs
    const unsigned* __restrict__ rp,         // row_ptr (possibly offset)
    const int* __restrict__ nbr,
    unsigned* __restrict__ outm)             // [nrows][64]
{
    int wave = threadIdx.x >> 6, lane = threadIdx.x & 63;
    int r = blockIdx.x * 4 + wave;
    unsigned beg = rp[r], end = rp[r + 1];
    float a0 = 0.f, a1 = 0.f;
    unsigned u = beg;
    for (; u + 4 <= end; u += 4) {
        int j0 = nbr[u], j1 = nbr[u + 1], j2 = nbr[u + 2], j3 = nbr[u + 3];
        unsigned p0 = src_rows[(size_t)j0 * 64 + lane];
        unsigned p1 = src_rows[(size_t)j1 * 64 + lane];
        unsigned p2 = src_rows[(size_t)j2 * 64 + lane];
        unsigned p3 = src_rows[(size_t)j3 * 64 + lane];
        a0 += bflo(p0) + bflo(p1) + bflo(p2) + bflo(p3);
        a1 += bfhi(p0) + bfhi(p1) + bfhi(p2) + bfhi(p3);
    }
    for (; u < end; ++u) {
        unsigned p = src_rows[(size_t)nbr[u] * 64 + lane];
        a0 += bflo(p); a1 += bfhi(p);
    }
    unsigned c = end - beg;
    float inv = 1.f / (float)(c ? c : 1u);
    outm[(size_t)r * 64 + lane] = packbf(a0 * inv, a1 * inv);
}

// ---------------- dual GEMM: out = relu(A1@WtA + A2@WtB + bias), bf16 out ----------------
template<bool A2F32>
__global__ __launch_bounds__(256) void gemmDual_kernel(
    const unsigned* __restrict__ A1,         // [M][64] bf16 pairs
    const void* __restrict__ A2,             // [M][64] u32 or [M][128] f32
    const unsigned short* __restrict__ WtA, const unsigned short* __restrict__ WtB,
    const float* __restrict__ bias, unsigned* __restrict__ Yout, int M)
{
    __shared__ char sW[65536];
    for (int c = threadIdx.x; c < 4096; c += 256)
        ((i32x4*)sW)[c] = (c < 2048) ? ((const i32x4*)WtA)[c] : ((const i32x4*)WtB)[c - 2048];
    __syncthreads();

    int wave = threadIdx.x >> 6, lane = threadIdx.x & 63;
    int ln = lane & 15, g = lane >> 4;
    int row = blockIdx.x * 64 + wave * 16 + ln;
    int rl = row < M ? row : M - 1;
    int swz = (ln & 7) << 4;

    f32x4 acc[8];
#pragma unroll
    for (int cf = 0; cf < 8; ++cf) acc[cf] = ((const f32x4*)bias)[cf * 4 + g];

    const i32x4* a1r = (const i32x4*)(A1 + (size_t)rl * 64);
#pragma unroll
    for (int ks = 0; ks < 4; ++ks) {
        Frag mf; mf.i = a1r[ks * 4 + g];
        Frag xf;
        if (A2F32) {
            const f32x4* xr = (const f32x4*)((const float*)A2 + (size_t)rl * 128);
            f32x4 fa = xr[ks * 8 + g * 2], fb = xr[ks * 8 + g * 2 + 1];
            i32x4 t = { (int)packbf(fa.x, fa.y), (int)packbf(fa.z, fa.w),
                        (int)packbf(fb.x, fb.y), (int)packbf(fb.z, fb.w) };
            xf.i = t;
        } else {
            xf.i = ((const i32x4*)((const unsigned*)A2 + (size_t)rl * 64))[ks * 4 + g];
        }
#pragma unroll
        for (int cf = 0; cf < 8; ++cf) {
            int off = (((cf * 16 + ln) << 8) + (ks << 6) + (g << 4)) ^ swz;
            Frag wa; wa.i = *(const i32x4*)(sW + off);
            Frag wb; wb.i = *(const i32x4*)(sW + 32768 + off);
            acc[cf] = __builtin_amdgcn_mfma_f32_16x16x32_bf16(wa.v, mf.v, acc[cf], 0, 0, 0);
            acc[cf] = __builtin_amdgcn_mfma_f32_16x16x32_bf16(wb.v, xf.v, acc[cf], 0, 0, 0);
        }
    }

    if (row < M) {
        unsigned* orow = Yout + (size_t)row * 64;
#pragma unroll
        for (int cf = 0; cf < 8; ++cf) {
            u32x2 o;
            o.x = packbf(fmaxf(acc[cf][0], 0.f), fmaxf(acc[cf][1], 0.f));
            o.y = packbf(fmaxf(acc[cf][2], 0.f), fmaxf(acc[cf][3], 0.f));
            *(u32x2*)(orow + cf * 8 + g * 2) = o;
        }
    }
}

// ---------------- tail: h2 = relu(meanH@W3l + sotu_h@W3r + b3) (LDS); out = h2@Wlin + blin ----------------
__global__ __launch_bounds__(256) void tail_kernel(
    const unsigned* __restrict__ meanH, const unsigned* __restrict__ sotu_h,
    const unsigned short* __restrict__ Wt3l, const unsigned short* __restrict__ Wt3r,
    const unsigned short* __restrict__ Wtlin,
    const float* __restrict__ b3, const float* __restrict__ blin,
    float* __restrict__ out, int M)
{
    __shared__ unsigned h2[64 * 64];   // 16KB, XOR-swizzled
    int wave = threadIdx.x >> 6, lane = threadIdx.x & 63;
    int ln = lane & 15, g = lane >> 4;
    int lrow = wave * 16 + ln;
    int row = blockIdx.x * 64 + lrow;

    f32x4 acc[8];
#pragma unroll
    for (int cf = 0; cf < 8; ++cf) acc[cf] = ((const f32x4*)b3)[cf * 4 + g];

    const i32x4* mr = (const i32x4*)(meanH + (size_t)row * 64);
    const i32x4* sr = (const i32x4*)(sotu_h + (size_t)row * 64);
#pragma unroll
    for (int ks = 0; ks < 4; ++ks) {
        Frag mf; mf.i = mr[ks * 4 + g];
        Frag sf; sf.i = sr[ks * 4 + g];
#pragma unroll
        for (int cf = 0; cf < 8; ++cf) {
            int col = cf * 16 + ln;
            Frag wl; wl.i = ldWfrag(Wt3l, col, ks, g);
            Frag wr; wr.i = ldWfrag(Wt3r, col, ks, g);
            acc[cf] = __builtin_amdgcn_mfma_f32_16x16x32_bf16(wl.v, mf.v, acc[cf], 0, 0, 0);
            acc[cf] = __builtin_amdgcn_mfma_f32_16x16x32_bf16(wr.v, sf.v, acc[cf], 0, 0, 0);
        }
    }
    int swz = (lrow & 7) << 2;
#pragma unroll
    for (int cf = 0; cf < 8; ++cf) {
        u32x2 o;
        o.x = packbf(fmaxf(acc[cf][0], 0.f), fmaxf(acc[cf][1], 0.f));
        o.y = packbf(fmaxf(acc[cf][2], 0.f), fmaxf(acc[cf][3], 0.f));
        *(u32x2*)&h2[lrow * 64 + ((cf * 8 + g * 2) ^ swz)] = o;
    }
    __syncthreads();

    f32x4 aL[4];
#pragma unroll
    for (int cf = 0; cf < 4; ++cf) aL[cf] = ((const f32x4*)blin)[cf * 4 + g];
#pragma unroll
    for (int ks = 0; ks < 4; ++ks) {
        Frag hf; hf.i = *(const i32x4*)&h2[lrow * 64 + ((ks * 16 + g * 4) ^ swz)];
#pragma unroll
        for (int cf = 0; cf < 4; ++cf) {
            Frag wf; wf.i = ldWfrag(Wtlin, cf * 16 + ln, ks, g);
            aL[cf] = __builtin_amdgcn_mfma_f32_16x16x32_bf16(wf.v, hf.v, aL[cf], 0, 0, 0);
        }
    }
    float* orow = out + (size_t)row * OUTC;
#pragma unroll
    for (int cf = 0; cf < 4; ++cf)
        *(f32x4*)(orow + cf * 16 + g * 4) = aL[cf];
}

extern "C" void kernel_launch(void* const* d_in, const int* in_sizes, int n_in,
                              void* d_out, int out_size, void* d_ws, size_t ws_size,
                              hipStream_t stream)
{
    const float* x_taxon = (const float*)d_in[0];
    const float* x_sotu  = (const float*)d_in[1];
    const int* hp_src = (const int*)d_in[2];
    const int* hp_dst = (const int*)d_in[3];
    const int* rh_src = (const int*)d_in[4];
    const int* rh_dst = (const int*)d_in[5];
    const float* W1l = (const float*)d_in[6];
    const float* W1r = (const float*)d_in[7];
    const float* b1  = (const float*)d_in[8];
    const float* W2l = (const float*)d_in[9];
    const float* W2r = (const float*)d_in[10];
    const float* b2  = (const float*)d_in[11];
    const float* W3l = (const float*)d_in[12];
    const float* W3r = (const float*)d_in[13];
    const float* b3  = (const float*)d_in[14];
    const float* Wlin = (const float*)d_in[15];
    const float* blin = (const float*)d_in[16];
    float* out = (float*)d_out;

    // ---- workspace layout (bytes), peak ~208 MB ----
    char* ws = (char*)d_ws;
    unsigned* xt_bf   = (unsigned*)(ws);                  // [100K][64] 25.6MB
    unsigned* taxon_h = (unsigned*)(ws + 25600000);       // 25.6MB
    unsigned* sotu_h  = (unsigned*)(ws);                  // 51.2MB overlays xt_bf+taxon_h
    unsigned* meanX   = (unsigned*)(ws + 51200000);       // [300K][64] 76.8MB
    unsigned* meanH   = (unsigned*)(ws + 128000000);      // [200K][64] 51.2MB
    unsigned long long* ebuf = (unsigned long long*)(ws + 179200000);  // 16MB
    int*      sorted_all = (int*)(ws + 195200000);        // 8.8MB
    unsigned* row_ptr = (unsigned*)(ws + 204000000);      // [300001]
    unsigned* cursor  = (unsigned*)(ws + 205200128);      // [300000]
    unsigned* cnt     = (unsigned*)(ws + 206400128);      // [300000]
    unsigned* bcnt    = (unsigned*)(ws + 207600128);      // [128]
    unsigned* bcursor = (unsigned*)(ws + 207600640);      // [128]
    unsigned* bstart  = (unsigned*)(ws + 207601152);      // [128]
    unsigned* bsum    = (unsigned*)(ws + 207601664);      // [2048]
    unsigned short* wtbase = (unsigned short*)(ws + 207609856);
    unsigned* cnt_t = cnt;
    unsigned* cnt_s = cnt + N_TAXON;
    unsigned short* Wt1l = wtbase;
    unsigned short* Wt1r = wtbase + 16384;
    unsigned short* Wt2l = wtbase + 32768;
    unsigned short* Wt2r = wtbase + 49152;
    unsigned short* Wt3l = wtbase + 65536;
    unsigned short* Wt3r = wtbase + 81920;
    unsigned short* Wtlin = wtbase + 98304;

    // zero cnt [300000] + bcnt [128] (contiguous)
    hipMemsetAsync(cnt, 0, 300000 * 4 + 512, stream);

    // ---- CSR build (unified 300K rows: hp rows 0..100K, rh rows 100K..300K) ----
    countAll_kernel<<<256, 256, 0, stream>>>(hp_dst, rh_dst, cnt_t, bcnt);
    scan98_kernel<<<1, 128, 0, stream>>>(bcnt, bcursor, bstart);
    partition_kernel<<<(E_RH + 4095) / 4096, 256, 0, stream>>>(rh_src, rh_dst, bcursor, cnt_s, ebuf, E_RH);
    {
        int n = N_TAXON + N_SOTU;
        int nb = (n + 255) / 256;   // 1172
        scanA_kernel<<<nb, 256, 0, stream>>>(cnt, bsum, n);
        scanB_kernel<<<1, 1024, 0, stream>>>(bsum, nb, row_ptr + n);
        scanC_kernel<<<nb, 256, 0, stream>>>(cnt, bsum, row_ptr, cursor, n);
    }
    fill_hp_kernel<<<782, 256, 0, stream>>>(hp_src, hp_dst, cursor, sorted_all);
    fillB_kernel<<<NBUCK, 256, 0, stream>>>(ebuf, row_ptr, bstart, sorted_all);

    // ---- weight prep + x_taxon cast ----
    wprep_all_kernel<<<(6 * 16384 + 8192 + 255) / 256, 256, 0, stream>>>(
        W1l, W1r, W2l, W2r, W3l, W3r, Wlin, wtbase);
    cast_kernel<<<25000, 256, 0, stream>>>(x_taxon, xt_bf, N_TAXON * 64);

    // ---- meanX over unified CSR (hp + rh in one dispatch, 300K rows) ----
    aggMean_kernel<<<(N_TAXON + N_SOTU) / 4, 256, 0, stream>>>(
        xt_bf, row_ptr, sorted_all, meanX);

    // ---- taxon_h = relu(meanX_hp@W1l + xt@W1r + b1) ----
    gemmDual_kernel<false><<<(N_TAXON + 63) / 64, 256, 0, stream>>>(
        meanX, xt_bf, Wt1l, Wt1r, b1, taxon_h, N_TAXON);

    // ---- meanH = mean_rh(taxon_h) ----
    aggMean_kernel<<<N_SOTU / 4, 256, 0, stream>>>(
        taxon_h, row_ptr + N_TAXON, sorted_all, meanH);

    // ---- sotu_h = relu(meanX_rh@W2l + x_sotu@W2r + b2) ----
    gemmDual_kernel<true><<<N_SOTU / 64, 256, 0, stream>>>(
        meanX + (size_t)N_TAXON * 64, x_sotu, Wt2l, Wt2r, b2, sotu_h, N_SOTU);

    // ---- tail: h2 (LDS) -> out ----
    tail_kernel<<<N_SOTU / 64, 256, 0, stream>>>(
        meanH, sotu_h, Wt3l, Wt3r, Wtlin, b3, blin, out, N_SOTU);
}

// Round 10
// 573.346 us; speedup vs baseline: 1.2257x; 1.0632x over previous
//
#include <hip/hip_runtime.h>
#include <hip/hip_bf16.h>

#define D 128
#define N_TAXON 100000
#define N_SOTU 200000
#define E_HP 200000
#define E_RH 2000000
#define OUTC 64
#define NBUCK 98      // ceil(N_SOTU / 2048)
#define BSHIFT 11

typedef __hip_bfloat16 bf16;
typedef __bf16 bf16v8 __attribute__((ext_vector_type(8)));
typedef float f32x4 __attribute__((ext_vector_type(4)));
typedef int i32x4 __attribute__((ext_vector_type(4)));
typedef unsigned u32x2 __attribute__((ext_vector_type(2)));

union Frag { i32x4 i; bf16v8 v; };

__device__ __forceinline__ float bflo(unsigned u) { return __uint_as_float(u << 16); }
__device__ __forceinline__ float bfhi(unsigned u) { return __uint_as_float(u & 0xffff0000u); }

__device__ __forceinline__ unsigned short f2bf(float x) {
    unsigned u = __float_as_uint(x);
    unsigned r = (u + 0x7fffu + ((u >> 16) & 1u)) >> 16;   // round-to-nearest-even
    return (unsigned short)r;
}
__device__ __forceinline__ unsigned packbf(float a, float b) {
    return (unsigned)f2bf(a) | ((unsigned)f2bf(b) << 16);
}

// weight a-frag read from pre-swizzled global image; frag = Wt[col][32ks+8g..+7]
__device__ __forceinline__ i32x4 ldWfrag(const unsigned short* __restrict__ Wt,
                                         int col, int ks, int g) {
    int off = ((col << 8) + (ks << 6) + (g << 4)) ^ ((col & 7) << 4);
    return *(const i32x4*)((const char*)Wt + off);
}

// ---------------- fused: hp degree + rh bucket histogram ----------------
__global__ __launch_bounds__(256) void countAll_kernel(const int* __restrict__ hp_dst,
                                                       const int* __restrict__ rh_dst,
                                                       unsigned* __restrict__ cnt_t,
                                                       unsigned* __restrict__ bcnt)
{
    __shared__ unsigned hist[NBUCK];
    if (threadIdx.x < NBUCK) hist[threadIdx.x] = 0;
    __syncthreads();
    int stride = gridDim.x * 256;
    for (int e = blockIdx.x * 256 + threadIdx.x; e < E_HP; e += stride)
        atomicAdd(&cnt_t[hp_dst[e]], 1u);
    for (int e = blockIdx.x * 256 + threadIdx.x; e < E_RH; e += stride)
        atomicAdd(&hist[rh_dst[e] >> BSHIFT], 1u);
    __syncthreads();
    if (threadIdx.x < NBUCK) atomicAdd(&bcnt[threadIdx.x], hist[threadIdx.x]);
}

// ---------------- tiny bucket prefix ----------------
__global__ __launch_bounds__(128) void scan98_kernel(const unsigned* __restrict__ bcnt,
                                                     unsigned* __restrict__ bcursor,
                                                     unsigned* __restrict__ bstart)
{
    __shared__ unsigned v[NBUCK];
    if (threadIdx.x < NBUCK) v[threadIdx.x] = bcnt[threadIdx.x];
    __syncthreads();
    if (threadIdx.x == 0) {
        unsigned acc = 0;
        for (int b = 0; b < NBUCK; ++b) {
            unsigned t = v[b];
            bcursor[b] = acc; bstart[b] = acc; acc += t;
        }
        bstart[NBUCK] = acc;
    }
}

// ---------------- rh: partition edges into dst-buckets + per-dst count ----------------
__global__ __launch_bounds__(256) void partition_kernel(
    const int* __restrict__ src, const int* __restrict__ dst,
    unsigned* __restrict__ bcursor, unsigned* __restrict__ cnt_s,
    unsigned long long* __restrict__ ebuf, int n)
{
    __shared__ unsigned hist[NBUCK];
    __shared__ unsigned lcur[NBUCK];
    int base = blockIdx.x * 4096;
    if (threadIdx.x < NBUCK) hist[threadIdx.x] = 0;
    __syncthreads();
    int s[16], d[16];
#pragma unroll
    for (int k = 0; k < 16; ++k) {
        int e = base + k * 256 + threadIdx.x;
        if (e < n) {
            s[k] = src[e]; d[k] = dst[e];
            atomicAdd(&hist[d[k] >> BSHIFT], 1u);
            atomicAdd(&cnt_s[d[k]], 1u);
        } else d[k] = -1;
    }
    __syncthreads();
    if (threadIdx.x < NBUCK)
        lcur[threadIdx.x] = atomicAdd(&bcursor[threadIdx.x], hist[threadIdx.x]);
    __syncthreads();
#pragma unroll
    for (int k = 0; k < 16; ++k) {
        if (d[k] >= 0) {
            unsigned slot = atomicAdd(&lcur[d[k] >> BSHIFT], 1u);
            ebuf[slot] = ((unsigned long long)(unsigned)d[k] << 32) | (unsigned)s[k];
        }
    }
}

// ---------------- combined 3-phase exclusive scan over [cnt_t ; cnt_s] ----------------
__global__ __launch_bounds__(256) void scanA_kernel(const unsigned* __restrict__ cnt,
                                                    unsigned* __restrict__ bsum, int n)
{
    int lane = threadIdx.x & 63, wv = threadIdx.x >> 6;
    __shared__ unsigned ws[4];
    int i = blockIdx.x * 256 + threadIdx.x;
    unsigned v = (i < n) ? cnt[i] : 0u;
    for (int off = 1; off < 64; off <<= 1) v += __shfl_xor(v, off, 64);
    if (lane == 0) ws[wv] = v;
    __syncthreads();
    if (threadIdx.x == 0) bsum[blockIdx.x] = ws[0] + ws[1] + ws[2] + ws[3];
}

__global__ __launch_bounds__(1024) void scanB_kernel(unsigned* __restrict__ bsum, int nb,
                                                     unsigned* __restrict__ total_out)
{
    int lane = threadIdx.x & 63, wv = threadIdx.x >> 6;
    __shared__ unsigned wsum[16];
    int t = threadIdx.x;
    unsigned v0 = (2 * t     < nb) ? bsum[2 * t]     : 0u;
    unsigned v1 = (2 * t + 1 < nb) ? bsum[2 * t + 1] : 0u;
    unsigned v = v0 + v1;
    unsigned s = v;
    for (int off = 1; off < 64; off <<= 1) {
        unsigned tt = __shfl_up(s, off, 64);
        if (lane >= off) s += tt;
    }
    if (lane == 63) wsum[wv] = s;
    __syncthreads();
    unsigned woff = 0, tot = 0;
    for (int w = 0; w < 16; ++w) { if (w < wv) woff += wsum[w]; tot += wsum[w]; }
    unsigned ex = woff + s - v;
    if (2 * t     < nb) bsum[2 * t]     = ex;
    if (2 * t + 1 < nb) bsum[2 * t + 1] = ex + v0;
    if (t == 0) *total_out = tot;
}

__global__ __launch_bounds__(256) void scanC_kernel(const unsigned* __restrict__ cnt,
                                                    const unsigned* __restrict__ bsum,
                                                    unsigned* __restrict__ row_ptr,
                                                    unsigned* __restrict__ cursor, int n)
{
    int lane = threadIdx.x & 63, wv = threadIdx.x >> 6;
    __shared__ unsigned wsum[4];
    int i = blockIdx.x * 256 + threadIdx.x;
    unsigned v = (i < n) ? cnt[i] : 0u;
    unsigned s = v;
    for (int off = 1; off < 64; off <<= 1) {
        unsigned t = __shfl_up(s, off, 64);
        if (lane >= off) s += t;
    }
    if (lane == 63) wsum[wv] = s;
    __syncthreads();
    unsigned woff = bsum[blockIdx.x];
    for (int w = 0; w < wv; ++w) woff += wsum[w];
    if (i < n) { unsigned p = woff + s - v; row_ptr[i] = p; cursor[i] = p; }
}

// ---------------- hp CSR fill (small, scattered is fine) ----------------
__global__ __launch_bounds__(256) void fill_hp_kernel(const int* __restrict__ src,
                                                      const int* __restrict__ dst,
                                                      unsigned* __restrict__ cursor,
                                                      int* __restrict__ sorted_all)
{
    int stride = gridDim.x * 256;
    for (int i = blockIdx.x * 256 + threadIdx.x; i < E_HP; i += stride) {
        unsigned pos = atomicAdd(&cursor[dst[i]], 1u);
        sorted_all[pos] = src[i];
    }
}

// ---------------- rh CSR fill: one block per bucket, LDS cursors, dense writes ----------------
__global__ __launch_bounds__(256) void fillB_kernel(const unsigned long long* __restrict__ ebuf,
                                                    const unsigned* __restrict__ row_ptr,
                                                    const unsigned* __restrict__ bstart,
                                                    int* __restrict__ sorted_all)
{
    __shared__ unsigned lcur[1 << BSHIFT];   // 8KB per-dst cursors for this bucket
    int c = blockIdx.x;
    int dbase = c << BSHIFT;
    for (int i = threadIdx.x; i < (1 << BSHIFT); i += 256) {
        int dd = dbase + i;
        lcur[i] = (dd < N_SOTU) ? row_ptr[N_TAXON + dd] : 0u;
    }
    __syncthreads();
    unsigned e0 = bstart[c], e1 = bstart[c + 1];
    for (unsigned e = e0 + threadIdx.x; e < e1; e += 256) {
        unsigned long long v = ebuf[e];
        unsigned dloc = (unsigned)(v >> 32) - dbase;
        unsigned pos = atomicAdd(&lcur[dloc], 1u);
        sorted_all[pos] = (int)(unsigned)v;
    }
}

// ---------------- all weights: transpose + bf16 + XOR-swizzle in one kernel ----------------
__global__ __launch_bounds__(256) void wprep_all_kernel(
    const float* __restrict__ W1l, const float* __restrict__ W1r,
    const float* __restrict__ W2l, const float* __restrict__ W2r,
    const float* __restrict__ W3l, const float* __restrict__ W3r,
    const float* __restrict__ Wlin, unsigned short* __restrict__ wtbase)
{
    int e = blockIdx.x * 256 + threadIdx.x;
    if (e >= 6 * 16384 + 8192) return;
    const float* srcs[7] = { W1l, W1r, W2l, W2r, W3l, W3r, Wlin };
    int m = e >> 14;
    int local = (m < 6) ? (e & 16383) : (e - 98304);
    int N = (m < 6) ? 128 : 64;
    int k = local / N, col = local - k * N;
    unsigned short* dst = wtbase + ((m < 6) ? m * 16384 : 98304);
    dst[(col * 128 + k) ^ ((col & 7) << 3)] = f2bf(srcs[m][local]);
}

// ---------------- cast x_taxon: f32 -> xt_bf (plain) + X2 even slots ----------------
__global__ __launch_bounds__(256) void cast2_kernel(const float* __restrict__ x,
                                                    unsigned* __restrict__ xt_bf,
                                                    unsigned* __restrict__ X2, int npairs)
{
    int stride = gridDim.x * 256;
    for (int i = blockIdx.x * 256 + threadIdx.x; i < npairs; i += stride) {
        float2 v = ((const float2*)x)[i];
        unsigned p = packbf(v.x, v.y);
        xt_bf[i] = p;
        X2[(size_t)(i >> 6) * 128 + ((i & 63) << 1)] = p;
    }
}

// ---------------- hp mean gather: meanX_hp[r] = mean_nbr(xt_bf) ----------------
__global__ __launch_bounds__(256) void aggMeanHp_kernel(
    const unsigned* __restrict__ src_rows, const unsigned* __restrict__ rp,
    const int* __restrict__ nbr, unsigned* __restrict__ outm)
{
    int wave = threadIdx.x >> 6, lane = threadIdx.x & 63;
    int r = blockIdx.x * 4 + wave;
    unsigned beg = rp[r], end = rp[r + 1];
    float a0 = 0.f, a1 = 0.f;
    unsigned u = beg;
    for (; u + 4 <= end; u += 4) {
        int j0 = nbr[u], j1 = nbr[u + 1], j2 = nbr[u + 2], j3 = nbr[u + 3];
        unsigned p0 = src_rows[(size_t)j0 * 64 + lane];
        unsigned p1 = src_rows[(size_t)j1 * 64 + lane];
        unsigned p2 = src_rows[(size_t)j2 * 64 + lane];
        unsigned p3 = src_rows[(size_t)j3 * 64 + lane];
        a0 += bflo(p0) + bflo(p1) + bflo(p2) + bflo(p3);
        a1 += bfhi(p0) + bfhi(p1) + bfhi(p2) + bfhi(p3);
    }
    for (; u < end; ++u) {
        unsigned p = src_rows[(size_t)nbr[u] * 64 + lane];
        a0 += bflo(p); a1 += bfhi(p);
    }
    unsigned c = end - beg;
    float inv = 1.f / (float)(c ? c : 1u);
    outm[(size_t)r * 64 + lane] = packbf(a0 * inv, a1 * inv);
}

// ---------------- taxon_h = relu(meanX_hp@W1l + xt@W1r + b1) -> X2 odd slots ----------------
__global__ __launch_bounds__(256) void gemmTh_kernel(
    const unsigned* __restrict__ A1, const unsigned* __restrict__ A2,
    const unsigned short* __restrict__ WtA, const unsigned short* __restrict__ WtB,
    const float* __restrict__ bias, unsigned* __restrict__ X2, int M)
{
    __shared__ char sW[65536];
    for (int c = threadIdx.x; c < 4096; c += 256)
        ((i32x4*)sW)[c] = (c < 2048) ? ((const i32x4*)WtA)[c] : ((const i32x4*)WtB)[c - 2048];
    __syncthreads();

    int wave = threadIdx.x >> 6, lane = threadIdx.x & 63;
    int ln = lane & 15, g = lane >> 4;
    int row = blockIdx.x * 64 + wave * 16 + ln;
    int rl = row < M ? row : M - 1;
    int swz = (ln & 7) << 4;

    f32x4 acc[8];
#pragma unroll
    for (int cf = 0; cf < 8; ++cf) acc[cf] = ((const f32x4*)bias)[cf * 4 + g];

    const i32x4* a1r = (const i32x4*)(A1 + (size_t)rl * 64);
    const i32x4* a2r = (const i32x4*)(A2 + (size_t)rl * 64);
#pragma unroll
    for (int ks = 0; ks < 4; ++ks) {
        Frag mf; mf.i = a1r[ks * 4 + g];
        Frag xf; xf.i = a2r[ks * 4 + g];
#pragma unroll
        for (int cf = 0; cf < 8; ++cf) {
            int off = (((cf * 16 + ln) << 8) + (ks << 6) + (g << 4)) ^ swz;
            Frag wa; wa.i = *(const i32x4*)(sW + off);
            Frag wb; wb.i = *(const i32x4*)(sW + 32768 + off);
            acc[cf] = __builtin_amdgcn_mfma_f32_16x16x32_bf16(wa.v, mf.v, acc[cf], 0, 0, 0);
            acc[cf] = __builtin_amdgcn_mfma_f32_16x16x32_bf16(wb.v, xf.v, acc[cf], 0, 0, 0);
        }
    }

    if (row < M) {
        unsigned* orow = X2 + (size_t)row * 128 + 1;
#pragma unroll
        for (int cf = 0; cf < 8; ++cf) {
            int p = cf * 8 + g * 2;
            orow[p * 2]       = packbf(fmaxf(acc[cf][0], 0.f), fmaxf(acc[cf][1], 0.f));
            orow[(p + 1) * 2] = packbf(fmaxf(acc[cf][2], 0.f), fmaxf(acc[cf][3], 0.f));
        }
    }
}

// ---------------- merged rh gather: meanXrh + meanH in ONE CSR walk over X2 ----------------
__global__ __launch_bounds__(256) void aggMean2_kernel(
    const unsigned* __restrict__ X2, const unsigned* __restrict__ rp,
    const int* __restrict__ nbr,
    unsigned* __restrict__ meanXrh, unsigned* __restrict__ meanH)
{
    int wave = threadIdx.x >> 6, lane = threadIdx.x & 63;
    int r = blockIdx.x * 4 + wave;
    unsigned beg = rp[r], end = rp[r + 1];
    float a0 = 0.f, a1 = 0.f, a2 = 0.f, a3 = 0.f;
    unsigned u = beg;
    for (; u + 2 <= end; u += 2) {
        int j0 = nbr[u], j1 = nbr[u + 1];
        u32x2 A = *(const u32x2*)(X2 + (size_t)j0 * 128 + lane * 2);
        u32x2 B = *(const u32x2*)(X2 + (size_t)j1 * 128 + lane * 2);
        a0 += bflo(A.x) + bflo(B.x); a1 += bfhi(A.x) + bfhi(B.x);
        a2 += bflo(A.y) + bflo(B.y); a3 += bfhi(A.y) + bfhi(B.y);
    }
    if (u < end) {
        u32x2 A = *(const u32x2*)(X2 + (size_t)nbr[u] * 128 + lane * 2);
        a0 += bflo(A.x); a1 += bfhi(A.x); a2 += bflo(A.y); a3 += bfhi(A.y);
    }
    unsigned c = end - beg;
    float inv = 1.f / (float)(c ? c : 1u);
    meanXrh[(size_t)r * 64 + lane] = packbf(a0 * inv, a1 * inv);
    meanH[(size_t)r * 64 + lane]   = packbf(a2 * inv, a3 * inv);
}

// ---------------- tail2: sotu_h (LDS) -> h2 (LDS) -> out, all uniform MFMA ----------------
__global__ __launch_bounds__(256) void tail2_kernel(
    const unsigned* __restrict__ meanXrh, const float* __restrict__ xs,
    const unsigned* __restrict__ meanH,
    const unsigned short* __restrict__ Wt2l, const unsigned short* __restrict__ Wt2r,
    const unsigned short* __restrict__ Wt3l, const unsigned short* __restrict__ Wt3r,
    const unsigned short* __restrict__ Wtlin,
    const float* __restrict__ b2, const float* __restrict__ b3,
    const float* __restrict__ blin, float* __restrict__ out)
{
    __shared__ unsigned sh[64 * 64];   // sotu_h tile, swizzled
    __shared__ unsigned h2[64 * 64];   // h2 tile, swizzled
    int wave = threadIdx.x >> 6, lane = threadIdx.x & 63;
    int ln = lane & 15, g = lane >> 4;
    int lrow = wave * 16 + ln;
    int row = blockIdx.x * 64 + lrow;
    int swz = (lrow & 7) << 2;

    // stage 0: sotu_h = relu(meanXrh@W2l + x_sotu@W2r + b2)
    f32x4 acc[8];
#pragma unroll
    for (int cf = 0; cf < 8; ++cf) acc[cf] = ((const f32x4*)b2)[cf * 4 + g];
    {
        const i32x4* mr = (const i32x4*)(meanXrh + (size_t)row * 64);
        const f32x4* xr = (const f32x4*)(xs + (size_t)row * 128);
#pragma unroll
        for (int ks = 0; ks < 4; ++ks) {
            Frag mf; mf.i = mr[ks * 4 + g];
            f32x4 fa = xr[ks * 8 + g * 2], fb = xr[ks * 8 + g * 2 + 1];
            Frag xf;
            i32x4 t = { (int)packbf(fa.x, fa.y), (int)packbf(fa.z, fa.w),
                        (int)packbf(fb.x, fb.y), (int)packbf(fb.z, fb.w) };
            xf.i = t;
#pragma unroll
            for (int cf = 0; cf < 8; ++cf) {
                int col = cf * 16 + ln;
                Frag wa; wa.i = ldWfrag(Wt2l, col, ks, g);
                Frag wb; wb.i = ldWfrag(Wt2r, col, ks, g);
                acc[cf] = __builtin_amdgcn_mfma_f32_16x16x32_bf16(wa.v, mf.v, acc[cf], 0, 0, 0);
                acc[cf] = __builtin_amdgcn_mfma_f32_16x16x32_bf16(wb.v, xf.v, acc[cf], 0, 0, 0);
            }
        }
    }
#pragma unroll
    for (int cf = 0; cf < 8; ++cf) {
        u32x2 o;
        o.x = packbf(fmaxf(acc[cf][0], 0.f), fmaxf(acc[cf][1], 0.f));
        o.y = packbf(fmaxf(acc[cf][2], 0.f), fmaxf(acc[cf][3], 0.f));
        *(u32x2*)&sh[lrow * 64 + ((cf * 8 + g * 2) ^ swz)] = o;
    }
    __syncthreads();

    // stage 1: h2 = relu(meanH@W3l + sotu_h@W3r + b3)
    f32x4 acc2[8];
#pragma unroll
    for (int cf = 0; cf < 8; ++cf) acc2[cf] = ((const f32x4*)b3)[cf * 4 + g];
    {
        const i32x4* hr = (const i32x4*)(meanH + (size_t)row * 64);
#pragma unroll
        for (int ks = 0; ks < 4; ++ks) {
            Frag mf; mf.i = hr[ks * 4 + g];
            Frag sf; sf.i = *(const i32x4*)&sh[lrow * 64 + ((ks * 16 + g * 4) ^ swz)];
#pragma unroll
            for (int cf = 0; cf < 8; ++cf) {
                int col = cf * 16 + ln;
                Frag wl; wl.i = ldWfrag(Wt3l, col, ks, g);
                Frag wr; wr.i = ldWfrag(Wt3r, col, ks, g);
                acc2[cf] = __builtin_amdgcn_mfma_f32_16x16x32_bf16(wl.v, mf.v, acc2[cf], 0, 0, 0);
                acc2[cf] = __builtin_amdgcn_mfma_f32_16x16x32_bf16(wr.v, sf.v, acc2[cf], 0, 0, 0);
            }
        }
    }
#pragma unroll
    for (int cf = 0; cf < 8; ++cf) {
        u32x2 o;
        o.x = packbf(fmaxf(acc2[cf][0], 0.f), fmaxf(acc2[cf][1], 0.f));
        o.y = packbf(fmaxf(acc2[cf][2], 0.f), fmaxf(acc2[cf][3], 0.f));
        *(u32x2*)&h2[lrow * 64 + ((cf * 8 + g * 2) ^ swz)] = o;
    }
    __syncthreads();

    // stage 2: out = h2 @ Wlin + blin
    f32x4 aL[4];
#pragma unroll
    for (int cf = 0; cf < 4; ++cf) aL[cf] = ((const f32x4*)blin)[cf * 4 + g];
#pragma unroll
    for (int ks = 0; ks < 4; ++ks) {
        Frag hf; hf.i = *(const i32x4*)&h2[lrow * 64 + ((ks * 16 + g * 4) ^ swz)];
#pragma unroll
        for (int cf = 0; cf < 4; ++cf) {
            Frag wf; wf.i = ldWfrag(Wtlin, cf * 16 + ln, ks, g);
            aL[cf] = __builtin_amdgcn_mfma_f32_16x16x32_bf16(wf.v, hf.v, aL[cf], 0, 0, 0);
        }
    }
    float* orow = out + (size_t)row * OUTC;
#pragma unroll
    for (int cf = 0; cf < 4; ++cf)
        *(f32x4*)(orow + cf * 16 + g * 4) = aL[cf];
}

extern "C" void kernel_launch(void* const* d_in, const int* in_sizes, int n_in,
                              void* d_out, int out_size, void* d_ws, size_t ws_size,
                              hipStream_t stream)
{
    const float* x_taxon = (const float*)d_in[0];
    const float* x_sotu  = (const float*)d_in[1];
    const int* hp_src = (const int*)d_in[2];
    const int* hp_dst = (const int*)d_in[3];
    const int* rh_src = (const int*)d_in[4];
    const int* rh_dst = (const int*)d_in[5];
    const float* W1l = (const float*)d_in[6];
    const float* W1r = (const float*)d_in[7];
    const float* b1  = (const float*)d_in[8];
    const float* W2l = (const float*)d_in[9];
    const float* W2r = (const float*)d_in[10];
    const float* b2  = (const float*)d_in[11];
    const float* W3l = (const float*)d_in[12];
    const float* W3r = (const float*)d_in[13];
    const float* b3  = (const float*)d_in[14];
    const float* Wlin = (const float*)d_in[15];
    const float* blin = (const float*)d_in[16];
    float* out = (float*)d_out;

    // ---- workspace layout (bytes), peak ~217.4 MB ----
    char* ws = (char*)d_ws;
    unsigned* X2      = (unsigned*)(ws);                  // [100K][128] xt|taxon_h interleaved
    unsigned* meanXrh = (unsigned*)(ws + 51200000);       // [200K][64]; ebuf overlays (dead first)
    unsigned* meanH   = (unsigned*)(ws + 102400000);      // [200K][64]
    unsigned* xt_bf   = (unsigned*)(ws + 153600000);      // [100K][64]
    unsigned* meanX_hp= (unsigned*)(ws + 179200000);      // [100K][64]
    unsigned long long* ebuf = (unsigned long long*)(ws + 51200000);  // 16MB, dead before meanXrh
    int*      sorted_all = (int*)(ws + 204800000);        // 8.8MB
    unsigned* row_ptr = (unsigned*)(ws + 213600000);      // [300001]
    unsigned* cursor  = (unsigned*)(ws + 214800128);      // [300000]
    unsigned* cnt     = (unsigned*)(ws + 216000128);      // [300000]
    unsigned* bcnt    = (unsigned*)(ws + 217200128);      // [128]
    unsigned* bcursor = (unsigned*)(ws + 217200640);      // [128]
    unsigned* bstart  = (unsigned*)(ws + 217201152);      // [128]
    unsigned* bsum    = (unsigned*)(ws + 217201664);      // [2048]
    unsigned short* wtbase = (unsigned short*)(ws + 217209856);
    unsigned* cnt_t = cnt;
    unsigned* cnt_s = cnt + N_TAXON;
    unsigned short* Wt1l = wtbase;
    unsigned short* Wt1r = wtbase + 16384;
    unsigned short* Wt2l = wtbase + 32768;
    unsigned short* Wt2r = wtbase + 49152;
    unsigned short* Wt3l = wtbase + 65536;
    unsigned short* Wt3r = wtbase + 81920;
    unsigned short* Wtlin = wtbase + 98304;

    // zero cnt [300000] + bcnt [128] (contiguous)
    hipMemsetAsync(cnt, 0, 300000 * 4 + 512, stream);

    // ---- CSR build (unified 300K rows: hp rows 0..100K, rh rows 100K..300K) ----
    countAll_kernel<<<256, 256, 0, stream>>>(hp_dst, rh_dst, cnt_t, bcnt);
    scan98_kernel<<<1, 128, 0, stream>>>(bcnt, bcursor, bstart);
    partition_kernel<<<(E_RH + 4095) / 4096, 256, 0, stream>>>(rh_src, rh_dst, bcursor, cnt_s, ebuf, E_RH);
    {
        int n = N_TAXON + N_SOTU;
        int nb = (n + 255) / 256;   // 1172
        scanA_kernel<<<nb, 256, 0, stream>>>(cnt, bsum, n);
        scanB_kernel<<<1, 1024, 0, stream>>>(bsum, nb, row_ptr + n);
        scanC_kernel<<<nb, 256, 0, stream>>>(cnt, bsum, row_ptr, cursor, n);
    }
    fill_hp_kernel<<<782, 256, 0, stream>>>(hp_src, hp_dst, cursor, sorted_all);
    fillB_kernel<<<NBUCK, 256, 0, stream>>>(ebuf, row_ptr, bstart, sorted_all);

    // ---- weight prep + x_taxon cast (xt_bf + X2 even slots) ----
    wprep_all_kernel<<<(6 * 16384 + 8192 + 255) / 256, 256, 0, stream>>>(
        W1l, W1r, W2l, W2r, W3l, W3r, Wlin, wtbase);
    cast2_kernel<<<25000, 256, 0, stream>>>(x_taxon, xt_bf, X2, N_TAXON * 64);

    // ---- meanX_hp over hp CSR ----
    aggMeanHp_kernel<<<N_TAXON / 4, 256, 0, stream>>>(xt_bf, row_ptr, sorted_all, meanX_hp);

    // ---- taxon_h = relu(meanX_hp@W1l + xt@W1r + b1) -> X2 odd slots ----
    gemmTh_kernel<<<(N_TAXON + 63) / 64, 256, 0, stream>>>(
        meanX_hp, xt_bf, Wt1l, Wt1r, b1, X2, N_TAXON);

    // ---- merged rh gather: meanXrh + meanH in one walk ----
    aggMean2_kernel<<<N_SOTU / 4, 256, 0, stream>>>(
        X2, row_ptr + N_TAXON, sorted_all, meanXrh, meanH);

    // ---- tail2: sotu_h (LDS) -> h2 (LDS) -> out ----
    tail2_kernel<<<N_SOTU / 64, 256, 0, stream>>>(
        meanXrh, x_sotu, meanH, Wt2l, Wt2r, Wt3l, Wt3r, Wtlin, b2, b3, blin, out);
}

// Round 11
// 530.774 us; speedup vs baseline: 1.3240x; 1.0802x over previous
//
#include <hip/hip_runtime.h>
#include <hip/hip_bf16.h>

#define D 128
#define N_TAXON 100000
#define N_SOTU 200000
#define E_HP 200000
#define E_RH 2000000
#define OUTC 64
#define NBUCK 98      // ceil(N_SOTU / 2048)
#define BSHIFT 11

typedef __hip_bfloat16 bf16;
typedef __bf16 bf16v8 __attribute__((ext_vector_type(8)));
typedef float f32x4 __attribute__((ext_vector_type(4)));
typedef int i32x4 __attribute__((ext_vector_type(4)));
typedef unsigned u32x2 __attribute__((ext_vector_type(2)));

union Frag { i32x4 i; bf16v8 v; };

__device__ __forceinline__ float bflo(unsigned u) { return __uint_as_float(u << 16); }
__device__ __forceinline__ float bfhi(unsigned u) { return __uint_as_float(u & 0xffff0000u); }

__device__ __forceinline__ unsigned short f2bf(float x) {
    unsigned u = __float_as_uint(x);
    unsigned r = (u + 0x7fffu + ((u >> 16) & 1u)) >> 16;   // round-to-nearest-even
    return (unsigned short)r;
}
__device__ __forceinline__ unsigned packbf(float a, float b) {
    return (unsigned)f2bf(a) | ((unsigned)f2bf(b) << 16);
}

// weight a-frag read from pre-swizzled global image; frag = Wt[col][32ks+8g..+7]
__device__ __forceinline__ i32x4 ldWfrag(const unsigned short* __restrict__ Wt,
                                         int col, int ks, int g) {
    int off = ((col << 8) + (ks << 6) + (g << 4)) ^ ((col & 7) << 4);
    return *(const i32x4*)((const char*)Wt + off);
}

// ---------------- fused: hp degree + rh bucket histogram ----------------
__global__ __launch_bounds__(256) void countAll_kernel(const int* __restrict__ hp_dst,
                                                       const int* __restrict__ rh_dst,
                                                       unsigned* __restrict__ cnt_t,
                                                       unsigned* __restrict__ bcnt)
{
    __shared__ unsigned hist[NBUCK];
    if (threadIdx.x < NBUCK) hist[threadIdx.x] = 0;
    __syncthreads();
    int stride = gridDim.x * 256;
    for (int e = blockIdx.x * 256 + threadIdx.x; e < E_HP; e += stride)
        atomicAdd(&cnt_t[hp_dst[e]], 1u);
    for (int e = blockIdx.x * 256 + threadIdx.x; e < E_RH; e += stride)
        atomicAdd(&hist[rh_dst[e] >> BSHIFT], 1u);
    __syncthreads();
    if (threadIdx.x < NBUCK) atomicAdd(&bcnt[threadIdx.x], hist[threadIdx.x]);
}

// ---------------- tiny bucket prefix (+ final row_ptr sentinel) ----------------
__global__ __launch_bounds__(128) void scan98_kernel(const unsigned* __restrict__ bcnt,
                                                     unsigned* __restrict__ bcursor,
                                                     unsigned* __restrict__ bstart,
                                                     unsigned* __restrict__ row_ptr)
{
    __shared__ unsigned v[NBUCK];
    if (threadIdx.x < NBUCK) v[threadIdx.x] = bcnt[threadIdx.x];
    __syncthreads();
    if (threadIdx.x == 0) {
        unsigned acc = 0;
        for (int b = 0; b < NBUCK; ++b) {
            unsigned t = v[b];
            bcursor[b] = acc; bstart[b] = acc; acc += t;
        }
        bstart[NBUCK] = acc;
        row_ptr[N_TAXON + N_SOTU] = E_HP + acc;   // sentinel
    }
}

// ---------------- rh: partition edges into dst-buckets (no global degree count) ----------------
__global__ __launch_bounds__(256) void partition_kernel(
    const int* __restrict__ src, const int* __restrict__ dst,
    unsigned* __restrict__ bcursor, unsigned long long* __restrict__ ebuf, int n)
{
    __shared__ unsigned hist[NBUCK];
    __shared__ unsigned lcur[NBUCK];
    int base = blockIdx.x * 4096;
    if (threadIdx.x < NBUCK) hist[threadIdx.x] = 0;
    __syncthreads();
    int s[16], d[16];
#pragma unroll
    for (int k = 0; k < 16; ++k) {
        int e = base + k * 256 + threadIdx.x;
        if (e < n) {
            s[k] = src[e]; d[k] = dst[e];
            atomicAdd(&hist[d[k] >> BSHIFT], 1u);
        } else d[k] = -1;
    }
    __syncthreads();
    if (threadIdx.x < NBUCK)
        lcur[threadIdx.x] = atomicAdd(&bcursor[threadIdx.x], hist[threadIdx.x]);
    __syncthreads();
#pragma unroll
    for (int k = 0; k < 16; ++k) {
        if (d[k] >= 0) {
            unsigned slot = atomicAdd(&lcur[d[k] >> BSHIFT], 1u);
            ebuf[slot] = ((unsigned long long)(unsigned)d[k] << 32) | (unsigned)s[k];
        }
    }
}

// ---------------- hp-only 3-phase exclusive scan ----------------
__global__ __launch_bounds__(256) void scanA_kernel(const unsigned* __restrict__ cnt,
                                                    unsigned* __restrict__ bsum, int n)
{
    int lane = threadIdx.x & 63, wv = threadIdx.x >> 6;
    __shared__ unsigned ws[4];
    int i = blockIdx.x * 256 + threadIdx.x;
    unsigned v = (i < n) ? cnt[i] : 0u;
    for (int off = 1; off < 64; off <<= 1) v += __shfl_xor(v, off, 64);
    if (lane == 0) ws[wv] = v;
    __syncthreads();
    if (threadIdx.x == 0) bsum[blockIdx.x] = ws[0] + ws[1] + ws[2] + ws[3];
}

__global__ __launch_bounds__(1024) void scanB_kernel(unsigned* __restrict__ bsum, int nb,
                                                     unsigned* __restrict__ total_out)
{
    int lane = threadIdx.x & 63, wv = threadIdx.x >> 6;
    __shared__ unsigned wsum[16];
    int t = threadIdx.x;
    unsigned v0 = (2 * t     < nb) ? bsum[2 * t]     : 0u;
    unsigned v1 = (2 * t + 1 < nb) ? bsum[2 * t + 1] : 0u;
    unsigned v = v0 + v1;
    unsigned s = v;
    for (int off = 1; off < 64; off <<= 1) {
        unsigned tt = __shfl_up(s, off, 64);
        if (lane >= off) s += tt;
    }
    if (lane == 63) wsum[wv] = s;
    __syncthreads();
    unsigned woff = 0, tot = 0;
    for (int w = 0; w < 16; ++w) { if (w < wv) woff += wsum[w]; tot += wsum[w]; }
    unsigned ex = woff + s - v;
    if (2 * t     < nb) bsum[2 * t]     = ex;
    if (2 * t + 1 < nb) bsum[2 * t + 1] = ex + v0;
    if (t == 0) *total_out = tot;
}

__global__ __launch_bounds__(256) void scanC_kernel(const unsigned* __restrict__ cnt,
                                                    const unsigned* __restrict__ bsum,
                                                    unsigned* __restrict__ row_ptr,
                                                    unsigned* __restrict__ cursor, int n)
{
    int lane = threadIdx.x & 63, wv = threadIdx.x >> 6;
    __shared__ unsigned wsum[4];
    int i = blockIdx.x * 256 + threadIdx.x;
    unsigned v = (i < n) ? cnt[i] : 0u;
    unsigned s = v;
    for (int off = 1; off < 64; off <<= 1) {
        unsigned t = __shfl_up(s, off, 64);
        if (lane >= off) s += t;
    }
    if (lane == 63) wsum[wv] = s;
    __syncthreads();
    unsigned woff = bsum[blockIdx.x];
    for (int w = 0; w < wv; ++w) woff += wsum[w];
    if (i < n) { unsigned p = woff + s - v; row_ptr[i] = p; cursor[i] = p; }
}

// ---------------- hp CSR fill (small, scattered is fine) ----------------
__global__ __launch_bounds__(256) void fill_hp_kernel(const int* __restrict__ src,
                                                      const int* __restrict__ dst,
                                                      unsigned* __restrict__ cursor,
                                                      int* __restrict__ sorted_all)
{
    int stride = gridDim.x * 256;
    for (int i = blockIdx.x * 256 + threadIdx.x; i < E_HP; i += stride) {
        unsigned pos = atomicAdd(&cursor[dst[i]], 1u);
        sorted_all[pos] = src[i];
    }
}

// ---------------- rh CSR fill: per-bucket LDS count + scan + row_ptr + fill ----------------
__global__ __launch_bounds__(256) void fillB_kernel(const unsigned long long* __restrict__ ebuf,
                                                    const unsigned* __restrict__ bstart,
                                                    unsigned* __restrict__ row_ptr,
                                                    int* __restrict__ sorted_all)
{
    __shared__ unsigned hist[1 << BSHIFT];   // 8KB: counts -> absolute cursors
    __shared__ unsigned wsum[4];
    int c = blockIdx.x;
    int dbase = c << BSHIFT;
    for (int i = threadIdx.x; i < (1 << BSHIFT); i += 256) hist[i] = 0;
    __syncthreads();
    unsigned e0 = bstart[c], e1 = bstart[c + 1];
    for (unsigned e = e0 + threadIdx.x; e < e1; e += 256)
        atomicAdd(&hist[(unsigned)(ebuf[e] >> 32) - dbase], 1u);
    __syncthreads();
    // intra-bucket exclusive scan over 2048 counters (thread t owns 8)
    int base8 = threadIdx.x * 8;
    unsigned loc[8], s = 0;
#pragma unroll
    for (int i = 0; i < 8; ++i) { loc[i] = s; s += hist[base8 + i]; }
    int lane = threadIdx.x & 63, wv = threadIdx.x >> 6;
    unsigned sc = s;
    for (int off = 1; off < 64; off <<= 1) {
        unsigned t = __shfl_up(sc, off, 64);
        if (lane >= off) sc += t;
    }
    if (lane == 63) wsum[wv] = sc;
    __syncthreads();
    unsigned woff = 0;
    for (int w = 0; w < wv; ++w) woff += wsum[w];
    unsigned tbase = E_HP + e0 + woff + sc - s;   // absolute exclusive prefix
#pragma unroll
    for (int i = 0; i < 8; ++i) {
        int dd = dbase + base8 + i;
        unsigned p = tbase + loc[i];
        if (dd < N_SOTU) row_ptr[N_TAXON + dd] = p;
        hist[base8 + i] = p;                      // becomes the fill cursor
    }
    __syncthreads();
    for (unsigned e = e0 + threadIdx.x; e < e1; e += 256) {
        unsigned long long v = ebuf[e];
        unsigned pos = atomicAdd(&hist[(unsigned)(v >> 32) - dbase], 1u);
        sorted_all[pos] = (int)(unsigned)v;
    }
}

// ---------------- all weights: transpose + bf16 + XOR-swizzle in one kernel ----------------
__global__ __launch_bounds__(256) void wprep_all_kernel(
    const float* __restrict__ W1l, const float* __restrict__ W1r,
    const float* __restrict__ W2l, const float* __restrict__ W2r,
    const float* __restrict__ W3l, const float* __restrict__ W3r,
    const float* __restrict__ Wlin, unsigned short* __restrict__ wtbase)
{
    int e = blockIdx.x * 256 + threadIdx.x;
    if (e >= 6 * 16384 + 8192) return;
    const float* srcs[7] = { W1l, W1r, W2l, W2r, W3l, W3r, Wlin };
    int m = e >> 14;
    int local = (m < 6) ? (e & 16383) : (e - 98304);
    int N = (m < 6) ? 128 : 64;
    int k = local / N, col = local - k * N;
    unsigned short* dst = wtbase + ((m < 6) ? m * 16384 : 98304);
    dst[(col * 128 + k) ^ ((col & 7) << 3)] = f2bf(srcs[m][local]);
}

// ---------------- hp mean gather from f32 x_taxon (XCD-swizzled) ----------------
__global__ __launch_bounds__(256) void aggMeanHp_kernel(
    const float* __restrict__ x, const unsigned* __restrict__ rp,
    const int* __restrict__ nbr, unsigned* __restrict__ outm)
{
    int wave = threadIdx.x >> 6, lane = threadIdx.x & 63;
    int bid = (blockIdx.x & 7) * 3125 + (blockIdx.x >> 3);   // grid = 25000
    int r = bid * 4 + wave;
    unsigned beg = rp[r], end = rp[r + 1];
    float a0 = 0.f, a1 = 0.f;
    unsigned u = beg;
    for (; u + 2 <= end; u += 2) {
        float2 A = ((const float2*)x)[(size_t)nbr[u] * 64 + lane];
        float2 B = ((const float2*)x)[(size_t)nbr[u + 1] * 64 + lane];
        a0 += A.x + B.x; a1 += A.y + B.y;
    }
    if (u < end) {
        float2 A = ((const float2*)x)[(size_t)nbr[u] * 64 + lane];
        a0 += A.x; a1 += A.y;
    }
    unsigned c = end - beg;
    float inv = 1.f / (float)(c ? c : 1u);
    outm[(size_t)r * 64 + lane] = packbf(a0 * inv, a1 * inv);
}

// ---------------- taxon_h GEMM; writes FULL X2 rows (even = bf16(x), odd = taxon_h) ----------------
__global__ __launch_bounds__(256) void gemmTh_kernel(
    const unsigned* __restrict__ A1 /*meanX_hp*/, const float* __restrict__ X /*x_taxon f32*/,
    const unsigned short* __restrict__ WtA, const unsigned short* __restrict__ WtB,
    const float* __restrict__ bias, unsigned* __restrict__ X2, int M)
{
    __shared__ char sW[65536];
    for (int c = threadIdx.x; c < 4096; c += 256)
        ((i32x4*)sW)[c] = (c < 2048) ? ((const i32x4*)WtA)[c] : ((const i32x4*)WtB)[c - 2048];
    __syncthreads();

    int wave = threadIdx.x >> 6, lane = threadIdx.x & 63;
    int ln = lane & 15, g = lane >> 4;
    int row = blockIdx.x * 64 + wave * 16 + ln;
    int rl = row < M ? row : M - 1;
    int swz = (ln & 7) << 4;

    f32x4 acc[8];
#pragma unroll
    for (int cf = 0; cf < 8; ++cf) acc[cf] = ((const f32x4*)bias)[cf * 4 + g];

    const i32x4* a1r = (const i32x4*)(A1 + (size_t)rl * 64);
    const f32x4* xr = (const f32x4*)(X + (size_t)rl * 128);
    unsigned* orow = X2 + (size_t)row * 128;
    i32x4 xpk[4];
#pragma unroll
    for (int ks = 0; ks < 4; ++ks) {
        Frag mf; mf.i = a1r[ks * 4 + g];
        f32x4 fa = xr[ks * 8 + g * 2], fb = xr[ks * 8 + g * 2 + 1];
        Frag xf;
        i32x4 t = { (int)packbf(fa.x, fa.y), (int)packbf(fa.z, fa.w),
                    (int)packbf(fb.x, fb.y), (int)packbf(fb.z, fb.w) };
        xf.i = t; xpk[ks] = t;
#pragma unroll
        for (int cf = 0; cf < 8; ++cf) {
            int off = (((cf * 16 + ln) << 8) + (ks << 6) + (g << 4)) ^ swz;
            Frag wa; wa.i = *(const i32x4*)(sW + off);
            Frag wb; wb.i = *(const i32x4*)(sW + 32768 + off);
            acc[cf] = __builtin_amdgcn_mfma_f32_16x16x32_bf16(wa.v, mf.v, acc[cf], 0, 0, 0);
            acc[cf] = __builtin_amdgcn_mfma_f32_16x16x32_bf16(wb.v, xf.v, acc[cf], 0, 0, 0);
        }
    }

    if (row < M) {
        // even slots: bf16(x) pairs (pair index 16ks+4g+j)
#pragma unroll
        for (int ks = 0; ks < 4; ++ks) {
            int p0 = 16 * ks + 4 * g;
            orow[(p0 + 0) * 2] = (unsigned)xpk[ks][0];
            orow[(p0 + 1) * 2] = (unsigned)xpk[ks][1];
            orow[(p0 + 2) * 2] = (unsigned)xpk[ks][2];
            orow[(p0 + 3) * 2] = (unsigned)xpk[ks][3];
        }
        // odd slots: taxon_h pairs (pair index cf*8+g*2 +{0,1})
#pragma unroll
        for (int cf = 0; cf < 8; ++cf) {
            int p = cf * 8 + g * 2;
            orow[p * 2 + 1]       = packbf(fmaxf(acc[cf][0], 0.f), fmaxf(acc[cf][1], 0.f));
            orow[(p + 1) * 2 + 1] = packbf(fmaxf(acc[cf][2], 0.f), fmaxf(acc[cf][3], 0.f));
        }
    }
}

// ---------------- merged rh gather: meanXrh + meanH in ONE walk (XCD-swizzled) ----------------
__global__ __launch_bounds__(256) void aggMean2_kernel(
    const unsigned* __restrict__ X2, const unsigned* __restrict__ rp,
    const int* __restrict__ nbr,
    unsigned* __restrict__ meanXrh, unsigned* __restrict__ meanH)
{
    int wave = threadIdx.x >> 6, lane = threadIdx.x & 63;
    int bid = (blockIdx.x & 7) * 6250 + (blockIdx.x >> 3);   // grid = 50000
    int r = bid * 4 + wave;
    unsigned beg = rp[r], end = rp[r + 1];
    float a0 = 0.f, a1 = 0.f, a2 = 0.f, a3 = 0.f;
    unsigned u = beg;
    for (; u + 2 <= end; u += 2) {
        int j0 = nbr[u], j1 = nbr[u + 1];
        u32x2 A = *(const u32x2*)(X2 + (size_t)j0 * 128 + lane * 2);
        u32x2 B = *(const u32x2*)(X2 + (size_t)j1 * 128 + lane * 2);
        a0 += bflo(A.x) + bflo(B.x); a1 += bfhi(A.x) + bfhi(B.x);
        a2 += bflo(A.y) + bflo(B.y); a3 += bfhi(A.y) + bfhi(B.y);
    }
    if (u < end) {
        u32x2 A = *(const u32x2*)(X2 + (size_t)nbr[u] * 128 + lane * 2);
        a0 += bflo(A.x); a1 += bfhi(A.x); a2 += bflo(A.y); a3 += bfhi(A.y);
    }
    unsigned c = end - beg;
    float inv = 1.f / (float)(c ? c : 1u);
    meanXrh[(size_t)r * 64 + lane] = packbf(a0 * inv, a1 * inv);
    meanH[(size_t)r * 64 + lane]   = packbf(a2 * inv, a3 * inv);
}

// ---------------- tail2: sotu_h (LDS) -> h2 (LDS) -> out, all uniform MFMA ----------------
__global__ __launch_bounds__(256) void tail2_kernel(
    const unsigned* __restrict__ meanXrh, const float* __restrict__ xs,
    const unsigned* __restrict__ meanH,
    const unsigned short* __restrict__ Wt2l, const unsigned short* __restrict__ Wt2r,
    const unsigned short* __restrict__ Wt3l, const unsigned short* __restrict__ Wt3r,
    const unsigned short* __restrict__ Wtlin,
    const float* __restrict__ b2, const float* __restrict__ b3,
    const float* __restrict__ blin, float* __restrict__ out)
{
    __shared__ unsigned sh[64 * 64];   // sotu_h tile, swizzled
    __shared__ unsigned h2[64 * 64];   // h2 tile, swizzled
    int wave = threadIdx.x >> 6, lane = threadIdx.x & 63;
    int ln = lane & 15, g = lane >> 4;
    int lrow = wave * 16 + ln;
    int row = blockIdx.x * 64 + lrow;
    int swz = (lrow & 7) << 2;

    // stage 0: sotu_h = relu(meanXrh@W2l + x_sotu@W2r + b2)
    f32x4 acc[8];
#pragma unroll
    for (int cf = 0; cf < 8; ++cf) acc[cf] = ((const f32x4*)b2)[cf * 4 + g];
    {
        const i32x4* mr = (const i32x4*)(meanXrh + (size_t)row * 64);
        const f32x4* xr = (const f32x4*)(xs + (size_t)row * 128);
#pragma unroll
        for (int ks = 0; ks < 4; ++ks) {
            Frag mf; mf.i = mr[ks * 4 + g];
            f32x4 fa = xr[ks * 8 + g * 2], fb = xr[ks * 8 + g * 2 + 1];
            Frag xf;
            i32x4 t = { (int)packbf(fa.x, fa.y), (int)packbf(fa.z, fa.w),
                        (int)packbf(fb.x, fb.y), (int)packbf(fb.z, fb.w) };
            xf.i = t;
#pragma unroll
            for (int cf = 0; cf < 8; ++cf) {
                int col = cf * 16 + ln;
                Frag wa; wa.i = ldWfrag(Wt2l, col, ks, g);
                Frag wb; wb.i = ldWfrag(Wt2r, col, ks, g);
                acc[cf] = __builtin_amdgcn_mfma_f32_16x16x32_bf16(wa.v, mf.v, acc[cf], 0, 0, 0);
                acc[cf] = __builtin_amdgcn_mfma_f32_16x16x32_bf16(wb.v, xf.v, acc[cf], 0, 0, 0);
            }
        }
    }
#pragma unroll
    for (int cf = 0; cf < 8; ++cf) {
        u32x2 o;
        o.x = packbf(fmaxf(acc[cf][0], 0.f), fmaxf(acc[cf][1], 0.f));
        o.y = packbf(fmaxf(acc[cf][2], 0.f), fmaxf(acc[cf][3], 0.f));
        *(u32x2*)&sh[lrow * 64 + ((cf * 8 + g * 2) ^ swz)] = o;
    }
    __syncthreads();

    // stage 1: h2 = relu(meanH@W3l + sotu_h@W3r + b3)
    f32x4 acc2[8];
#pragma unroll
    for (int cf = 0; cf < 8; ++cf) acc2[cf] = ((const f32x4*)b3)[cf * 4 + g];
    {
        const i32x4* hr = (const i32x4*)(meanH + (size_t)row * 64);
#pragma unroll
        for (int ks = 0; ks < 4; ++ks) {
            Frag mf; mf.i = hr[ks * 4 + g];
            Frag sf; sf.i = *(const i32x4*)&sh[lrow * 64 + ((ks * 16 + g * 4) ^ swz)];
#pragma unroll
            for (int cf = 0; cf < 8; ++cf) {
                int col = cf * 16 + ln;
                Frag wl; wl.i = ldWfrag(Wt3l, col, ks, g);
                Frag wr; wr.i = ldWfrag(Wt3r, col, ks, g);
                acc2[cf] = __builtin_amdgcn_mfma_f32_16x16x32_bf16(wl.v, mf.v, acc2[cf], 0, 0, 0);
                acc2[cf] = __builtin_amdgcn_mfma_f32_16x16x32_bf16(wr.v, sf.v, acc2[cf], 0, 0, 0);
            }
        }
    }
#pragma unroll
    for (int cf = 0; cf < 8; ++cf) {
        u32x2 o;
        o.x = packbf(fmaxf(acc2[cf][0], 0.f), fmaxf(acc2[cf][1], 0.f));
        o.y = packbf(fmaxf(acc2[cf][2], 0.f), fmaxf(acc2[cf][3], 0.f));
        *(u32x2*)&h2[lrow * 64 + ((cf * 8 + g * 2) ^ swz)] = o;
    }
    __syncthreads();

    // stage 2: out = h2 @ Wlin + blin
    f32x4 aL[4];
#pragma unroll
    for (int cf = 0; cf < 4; ++cf) aL[cf] = ((const f32x4*)blin)[cf * 4 + g];
#pragma unroll
    for (int ks = 0; ks < 4; ++ks) {
        Frag hf; hf.i = *(const i32x4*)&h2[lrow * 64 + ((ks * 16 + g * 4) ^ swz)];
#pragma unroll
        for (int cf = 0; cf < 4; ++cf) {
            Frag wf; wf.i = ldWfrag(Wtlin, cf * 16 + ln, ks, g);
            aL[cf] = __builtin_amdgcn_mfma_f32_16x16x32_bf16(wf.v, hf.v, aL[cf], 0, 0, 0);
        }
    }
    float* orow = out + (size_t)row * OUTC;
#pragma unroll
    for (int cf = 0; cf < 4; ++cf)
        *(f32x4*)(orow + cf * 16 + g * 4) = aL[cf];
}

extern "C" void kernel_launch(void* const* d_in, const int* in_sizes, int n_in,
                              void* d_out, int out_size, void* d_ws, size_t ws_size,
                              hipStream_t stream)
{
    const float* x_taxon = (const float*)d_in[0];
    const float* x_sotu  = (const float*)d_in[1];
    const int* hp_src = (const int*)d_in[2];
    const int* hp_dst = (const int*)d_in[3];
    const int* rh_src = (const int*)d_in[4];
    const int* rh_dst = (const int*)d_in[5];
    const float* W1l = (const float*)d_in[6];
    const float* W1r = (const float*)d_in[7];
    const float* b1  = (const float*)d_in[8];
    const float* W2l = (const float*)d_in[9];
    const float* W2r = (const float*)d_in[10];
    const float* b2  = (const float*)d_in[11];
    const float* W3l = (const float*)d_in[12];
    const float* W3r = (const float*)d_in[13];
    const float* b3  = (const float*)d_in[14];
    const float* Wlin = (const float*)d_in[15];
    const float* blin = (const float*)d_in[16];
    float* out = (float*)d_out;

    // ---- workspace layout (bytes), peak ~190.3 MB ----
    char* ws = (char*)d_ws;
    unsigned* X2      = (unsigned*)(ws);                  // [100K][128] xt|taxon_h interleaved
    unsigned* meanXrh = (unsigned*)(ws + 51200000);       // [200K][64]; ebuf overlays (dead first)
    unsigned* meanH   = (unsigned*)(ws + 102400000);      // [200K][64]
    unsigned* meanX_hp= (unsigned*)(ws + 153600000);      // [100K][64]
    unsigned long long* ebuf = (unsigned long long*)(ws + 51200000);  // 16MB, dead before aggMean2
    int*      sorted_all = (int*)(ws + 179200000);        // 8.8MB
    unsigned* row_ptr = (unsigned*)(ws + 188000000);      // [300001]
    unsigned* cursor  = (unsigned*)(ws + 189200128);      // [100000]
    unsigned* cnt_t   = (unsigned*)(ws + 189600128);      // [100000]
    unsigned* bcnt    = (unsigned*)(ws + 190000128);      // [128]
    unsigned* bcursor = (unsigned*)(ws + 190000640);      // [128]
    unsigned* bstart  = (unsigned*)(ws + 190001152);      // [128]
    unsigned* bsum    = (unsigned*)(ws + 190001664);      // [2048]
    unsigned short* wtbase = (unsigned short*)(ws + 190009856);
    unsigned short* Wt1l = wtbase;
    unsigned short* Wt1r = wtbase + 16384;
    unsigned short* Wt2l = wtbase + 32768;
    unsigned short* Wt2r = wtbase + 49152;
    unsigned short* Wt3l = wtbase + 65536;
    unsigned short* Wt3r = wtbase + 81920;
    unsigned short* Wtlin = wtbase + 98304;

    // zero cnt_t [100000] + bcnt [128] (contiguous)
    hipMemsetAsync(cnt_t, 0, 100000 * 4 + 512, stream);

    // ---- CSR build ----
    countAll_kernel<<<256, 256, 0, stream>>>(hp_dst, rh_dst, cnt_t, bcnt);
    scan98_kernel<<<1, 128, 0, stream>>>(bcnt, bcursor, bstart, row_ptr);
    partition_kernel<<<(E_RH + 4095) / 4096, 256, 0, stream>>>(rh_src, rh_dst, bcursor, ebuf, E_RH);
    {
        int nb = (N_TAXON + 255) / 256;   // 391
        scanA_kernel<<<nb, 256, 0, stream>>>(cnt_t, bsum, N_TAXON);
        scanB_kernel<<<1, 1024, 0, stream>>>(bsum, nb, row_ptr + N_TAXON);
        scanC_kernel<<<nb, 256, 0, stream>>>(cnt_t, bsum, row_ptr, cursor, N_TAXON);
    }
    fill_hp_kernel<<<782, 256, 0, stream>>>(hp_src, hp_dst, cursor, sorted_all);
    fillB_kernel<<<NBUCK, 256, 0, stream>>>(ebuf, bstart, row_ptr, sorted_all);

    // ---- weight prep ----
    wprep_all_kernel<<<(6 * 16384 + 8192 + 255) / 256, 256, 0, stream>>>(
        W1l, W1r, W2l, W2r, W3l, W3r, Wlin, wtbase);

    // ---- meanX_hp over hp CSR (f32 source) ----
    aggMeanHp_kernel<<<N_TAXON / 4, 256, 0, stream>>>(x_taxon, row_ptr, sorted_all, meanX_hp);

    // ---- taxon_h GEMM -> full X2 rows ----
    gemmTh_kernel<<<(N_TAXON + 63) / 64, 256, 0, stream>>>(
        meanX_hp, x_taxon, Wt1l, Wt1r, b1, X2, N_TAXON);

    // ---- merged rh gather: meanXrh + meanH in one walk ----
    aggMean2_kernel<<<N_SOTU / 4, 256, 0, stream>>>(
        X2, row_ptr + N_TAXON, sorted_all, meanXrh, meanH);

    // ---- tail2: sotu_h (LDS) -> h2 (LDS) -> out ----
    tail2_kernel<<<N_SOTU / 64, 256, 0, stream>>>(
        meanXrh, x_sotu, meanH, Wt2l, Wt2r, Wt3l, Wt3r, Wtlin, b2, b3, blin, out);
}